// Round 1
// baseline (270.100 us; speedup 1.0000x reference)
//
#include <hip/hip_runtime.h>
#include <math.h>

#define NB 8
#define NA 512
#define NN 64
#define ND 128
#define NF 128
#define NG 25
#define NGA 512

typedef __attribute__((ext_vector_type(8))) short bf16x8;
typedef __attribute__((ext_vector_type(4))) float f32x4;

__device__ __forceinline__ float sspf(float v) {
  return fmaxf(v, 0.0f) + __logf(1.0f + __expf(-fabsf(v))) - 0.6931471805599453f;
}

__device__ __forceinline__ short f2bf(float x) {
  union { float f; unsigned u; } v; v.f = x;
  unsigned r = v.u + 0x7fffu + ((v.u >> 16) & 1u);   // RNE
  return (short)(r >> 16);
}

#if defined(__has_builtin)
#if __has_builtin(__builtin_amdgcn_cvt_pk_bf16_f32)
#define HAS_PKBF 1
#endif
#endif

__device__ __forceinline__ unsigned pk2bf(float a, float b) {
#ifdef HAS_PKBF
  typedef __attribute__((ext_vector_type(2))) __bf16 v2bf;
  union { v2bf v; unsigned u; } c;
  c.v = __builtin_amdgcn_cvt_pk_bf16_f32(a, b);
  return c.u;
#else
  union { float f; unsigned u; } x, y; x.f = a; y.f = b;
  const unsigned ra = (x.u + 0x7fffu + ((x.u >> 16) & 1u)) >> 16;
  const unsigned rb = (y.u + 0x7fffu + ((y.u >> 16) & 1u)) & 0xffff0000u;
  return ra | rb;
#endif
}

__device__ __forceinline__ float bf2f(unsigned short us) {
  union { unsigned u; float f; } v; v.u = ((unsigned)us) << 16; return v.f;
}

__device__ __forceinline__ bf16x8 pack8(float4 a, float4 b) {
  bf16x8 r;
  unsigned* p = (unsigned*)&r;
  p[0] = pk2bf(a.x, a.y); p[1] = pk2bf(a.z, a.w);
  p[2] = pk2bf(b.x, b.y); p[3] = pk2bf(b.z, b.w);
  return r;
}

// W^T-style fragment built from row-major M[k][n]: elem i = bf16(M[k0q+i][n])
__device__ __forceinline__ bf16x8 fragT(const float* __restrict__ M, int ldn,
                                        int n, int k0q) {
  float e[8];
#pragma unroll
  for (int i = 0; i < 8; ++i) e[i] = M[(size_t)(k0q + i) * ldn + n];
  bf16x8 r; unsigned* p = (unsigned*)&r;
  p[0] = pk2bf(e[0], e[1]); p[1] = pk2bf(e[2], e[3]);
  p[2] = pk2bf(e[4], e[5]); p[3] = pk2bf(e[6], e[7]);
  return r;
}

#define NW1 (3 * 128 * 32)      // 12288
#define NSQ (3 * 128 * 128)     // 49152
// k_prep grid layout (all blocks independent):
#define TT_BLK 96               // 6 square mats x 16 (32x32) tiles
#define W1_BLK 48               // w1T scalar transpose
#define PF_BLK 24               // W12 fuse
#define VA_BLK 768              // vang direct
#define Y0_BLK 256              // y0 + x init
#define B_W1 (TT_BLK)
#define B_PF (B_W1 + W1_BLK)
#define B_VA (B_PF + PF_BLK)
#define B_Y0 (B_VA + VA_BLK)
#define PREP_BLK (B_Y0 + Y0_BLK)   // 1192

// ================= single prep kernel: no inter-block dependencies =========
__global__ __launch_bounds__(256) void k_prep(
    const float* __restrict__ fw1, const float* __restrict__ fw2,
    const float* __restrict__ in2f, const float* __restrict__ aw,
    const float* __restrict__ f2o, const float* __restrict__ f2ob,
    const float* __restrict__ dw, const float* __restrict__ db,
    const float* __restrict__ emb, const float* __restrict__ Gi,
    const int* __restrict__ zn,
    short* __restrict__ w1T, short* __restrict__ w2T,
    short* __restrict__ in2fT, short* __restrict__ W12T,
    float* __restrict__ b12, short* __restrict__ vangB,
    float* __restrict__ x, short* __restrict__ yB) {
  __shared__ short sTile[32][33];
  const int bx = blockIdx.x;
  const int t = threadIdx.x;
  const int lane = t & 63, wave = t >> 6;
  const int lanelo = lane & 15, quad = lane >> 4;
  const int wbase = wave << 5;

  if (bx < TT_BLK) {
    // ---- tiled transpose: fw2 -> w2T, in2f -> in2fT (bf16, [n][k]) ----
    const int mat = bx >> 4, tile = bx & 15;
    const int l = mat >> 1, which = mat & 1;
    const float* src = (which ? in2f : fw2) + (size_t)l * 16384;
    short* dst = (which ? in2fT : w2T) + (size_t)l * 16384;
    const int tk0 = (tile >> 2) << 5, tn0 = (tile & 3) << 5;
    const int tr = t >> 3, tc4 = (t & 7) << 2;
    const float4 v = *(const float4*)(src + (size_t)(tk0 + tr) * 128 + tn0 + tc4);
    sTile[tr][tc4] = f2bf(v.x); sTile[tr][tc4 + 1] = f2bf(v.y);
    sTile[tr][tc4 + 2] = f2bf(v.z); sTile[tr][tc4 + 3] = f2bf(v.w);
    __syncthreads();
    short o[4];
#pragma unroll
    for (int j = 0; j < 4; ++j) o[j] = sTile[tc4 + j][tr];
    uint2 pk;
    pk.x = ((unsigned)(unsigned short)o[0]) | (((unsigned)(unsigned short)o[1]) << 16);
    pk.y = ((unsigned)(unsigned short)o[2]) | (((unsigned)(unsigned short)o[3]) << 16);
    *(uint2*)(dst + (size_t)(tn0 + tr) * 128 + tk0 + tc4) = pk;
    return;
  }
  if (bx < B_PF) {
    // ---- w1T[l][n][k] (k padded 25->32) ----
    const int idx = (bx - B_W1) * 256 + t;
    const int l = idx >> 12, r = idx & 4095, n = r >> 5, k = r & 31;
    w1T[idx] = (k < NG) ? f2bf(fw1[(size_t)l * NG * NF + k * NF + n]) : (short)0;
    return;
  }
  if (bx < B_VA) {
    // ---- W12 = f2o@dw (bf16 [j][i]), b12 = f2ob@dw + db ----
    const int fb = bx - B_PF;
    const int l = fb >> 3, xi = fb & 7;
    const int i = (xi << 4) + lanelo;
    const float* f2o_l = f2o + (size_t)l * 16384;
    const float* dw_l = dw + (size_t)l * 16384;
    short* W12T_l = W12T + (size_t)l * 16384;
    f32x4 c[2] = {{0.f, 0.f, 0.f, 0.f}, {0.f, 0.f, 0.f, 0.f}};
#pragma unroll
    for (int kt = 0; kt < 4; ++kt) {
      const int k0 = kt * 32 + quad * 8;
      const bf16x8 b = pack8(*(const float4*)(f2o_l + (size_t)i * 128 + k0),
                             *(const float4*)(f2o_l + (size_t)i * 128 + k0 + 4));
#pragma unroll
      for (int ct = 0; ct < 2; ++ct) {
        const bf16x8 a = fragT(dw_l, 128, wbase + ct * 16 + lanelo, k0);
        c[ct] = __builtin_amdgcn_mfma_f32_16x16x32_bf16(a, b, c[ct], 0, 0, 0);
      }
    }
#pragma unroll
    for (int ct = 0; ct < 2; ++ct)
#pragma unroll
      for (int reg = 0; reg < 4; ++reg) {
        const int j = wbase + ct * 16 + quad * 4 + reg;
        W12T_l[(size_t)j * 128 + i] = f2bf(c[ct][reg]);
      }
    if (xi == 0 && t < 128) {
      float acc = db[(size_t)l * 128 + t];
      for (int k = 0; k < 128; ++k)
        acc += f2ob[(size_t)l * 128 + k] * dw_l[(size_t)k * 128 + t];
      b12[(size_t)l * 128 + t] = acc;
    }
    return;
  }
  if (bx < B_Y0) {
    // ---- vangB[l] = bf16(bf16(Gi) @ bf16(aw[l])) ----
    const int vb = bx - B_VA;
    const int l = vb >> 8;
    const int row = ((vb & 255) << 4) + lanelo;
    const float* aw_l = aw + (size_t)l * 65536;
    f32x4 c[2] = {{0.f, 0.f, 0.f, 0.f}, {0.f, 0.f, 0.f, 0.f}};
#pragma unroll
    for (int kt = 0; kt < 16; ++kt) {
      const int k0 = kt * 32 + quad * 8;
      const bf16x8 b = pack8(*(const float4*)(Gi + (size_t)row * NGA + k0),
                             *(const float4*)(Gi + (size_t)row * NGA + k0 + 4));
#pragma unroll
      for (int ct = 0; ct < 2; ++ct) {
        const bf16x8 a = fragT(aw_l, 128, wbase + ct * 16 + lanelo, k0);
        c[ct] = __builtin_amdgcn_mfma_f32_16x16x32_bf16(a, b, c[ct], 0, 0, 0);
      }
    }
    short* vrow = vangB + ((size_t)l * NB * NA + row) * 128;
#pragma unroll
    for (int ct = 0; ct < 2; ++ct) {
      uint2 pk; pk.x = pk2bf(c[ct][0], c[ct][1]); pk.y = pk2bf(c[ct][2], c[ct][3]);
      *(uint2*)(vrow + wbase + ct * 16 + quad * 4) = pk;
    }
    return;
  }
  // ---- y0 = bf16(emb[zn] @ in2f[0]); wave 0 also writes x = emb[zn] ----
  {
    const int row = ((bx - B_Y0) << 4) + lanelo;
    const float* erow = emb + (size_t)zn[row] * ND;
    f32x4 c[2] = {{0.f, 0.f, 0.f, 0.f}, {0.f, 0.f, 0.f, 0.f}};
#pragma unroll
    for (int kt = 0; kt < 4; ++kt) {
      const int k0 = kt * 32 + quad * 8;
      const float4 e0 = *(const float4*)(erow + k0);
      const float4 e1 = *(const float4*)(erow + k0 + 4);
      if (wave == 0) {
        *(float4*)(x + (size_t)row * ND + k0) = e0;
        *(float4*)(x + (size_t)row * ND + k0 + 4) = e1;
      }
      const bf16x8 b = pack8(e0, e1);
#pragma unroll
      for (int ct = 0; ct < 2; ++ct) {
        const bf16x8 a = fragT(in2f, 128, wbase + ct * 16 + lanelo, k0);
        c[ct] = __builtin_amdgcn_mfma_f32_16x16x32_bf16(a, b, c[ct], 0, 0, 0);
      }
    }
#pragma unroll
    for (int ct = 0; ct < 2; ++ct) {
      const int c0 = wbase + ct * 16 + quad * 4;
      uint2 pk; pk.x = pk2bf(c[ct][0], c[ct][1]); pk.y = pk2bf(c[ct][2], c[ct][3]);
      *(uint2*)(yB + (size_t)row * 128 + c0) = pk;
    }
  }
}

// ====== fused CFConv + interaction update (one block per atom) =============
// cfconv: compacted valid neighbors -> 16-row tiles; agg reduced in-wave.
// update: agg -> LDS; v_rad = W12 @ agg (broadcast-B MFMA); x += ssp(...);
//         y_next = in2f[l+1] @ x_new, written to the OTHER y buffer
//         (double-buffered: same-kernel blocks still read yIn of neighbors).
#define HPAD 136
__global__ __launch_bounds__(256) void k_fused(
    const float* __restrict__ pos, const int* __restrict__ nbr,
    const int* __restrict__ nmask, const short* __restrict__ yIn,
    const short* __restrict__ w1T, const float* __restrict__ b1,
    const short* __restrict__ w2T, const float* __restrict__ b2,
    float* __restrict__ x, const short* __restrict__ vangL,
    const short* __restrict__ W12Tl, const float* __restrict__ b12l,
    const short* __restrict__ in2fTn, short* __restrict__ yOut) {
  __shared__ alignas(16) short sH[NN * HPAD];
  __shared__ float sR[NN];
  __shared__ float sScale[NN];
  __shared__ int sNbr[NN];
  __shared__ int sNv;
  __shared__ alignas(16) float sAgg[NF];
  __shared__ alignas(16) float sXn[ND];

  const int t = threadIdx.x;
  const int ga = blockIdx.x;
  const int b0 = ga & ~(NA - 1);
  const int lane = t & 63;
  const int wave = t >> 6;
  const int lanelo = lane & 15;
  const int quad = lane >> 4;
  const int wbase = wave << 5;     // this wave's 32 f-cols

  bf16x8 bw1[2];
  bf16x8 bw2[8];
#pragma unroll
  for (int ct = 0; ct < 2; ++ct) {
    const int n = wbase + ct * 16 + lanelo;
    bw1[ct] = *(const bf16x8*)(w1T + n * 32 + quad * 8);
#pragma unroll
    for (int kt = 0; kt < 4; ++kt)
      bw2[ct * 4 + kt] = *(const bf16x8*)(w2T + n * 128 + kt * 32 + quad * 8);
  }
  float b2r[2];
#pragma unroll
  for (int ct = 0; ct < 2; ++ct) b2r[ct] = b2[wbase + ct * 16 + lanelo];
  float4 b1v[2];
#pragma unroll
  for (int ct = 0; ct < 2; ++ct)
    b1v[ct] = *(const float4*)(b1 + wbase + ct * 16 + quad * 4);

  // ---- wave 0: distances + ballot compaction ----
  if (t < NN) {
    const int nj = nbr[(size_t)ga * NN + t];
    const float px = pos[(size_t)ga * 3];
    const float py = pos[(size_t)ga * 3 + 1];
    const float pz = pos[(size_t)ga * 3 + 2];
    const float* pj = pos + (size_t)(b0 + nj) * 3;
    const float dx = pj[0] - px, dy = pj[1] - py, dz = pj[2] - pz;
    const float r = sqrtf(dx * dx + dy * dy + dz * dz + 1e-12f);
    const bool valid = (r <= 5.0f) && (nmask[(size_t)ga * NN + t] != 0);
    sR[t] = 1.0f; sScale[t] = 0.0f; sNbr[t] = 0;
    const unsigned long long m = __ballot(valid);
    const int pos_c = __popcll(m & ((1ull << lane) - 1ull));
    if (valid) { sNbr[pos_c] = nj; sR[pos_c] = r; sScale[pos_c] = 1.0f; }
    if (lane == 0) sNv = (int)__popcll(m);
  }
  __syncthreads();

  const int ntiles = (sNv + 15) >> 4;

  const float step = 3.8f / 24.0f;
  const float coef = -0.5f / (step * step);

  // ---- phase 1: h = ssp(f @ w1 + b1) for compacted tiles ----
  for (int jt = 0; jt < ntiles; ++jt) {
    const int j = jt * 16 + lanelo;
    const float r = sR[j];
    bf16x8 gb;
    {
      float e[8];
#pragma unroll
      for (int i = 0; i < 8; ++i) {
        const int g = quad * 8 + i;
        const float d = r - (1.2f + step * (float)g);
        e[i] = (g < NG) ? __expf(coef * d * d) : 0.0f;
      }
      unsigned* gp = (unsigned*)&gb;
      gp[0] = pk2bf(e[0], e[1]); gp[1] = pk2bf(e[2], e[3]);
      gp[2] = pk2bf(e[4], e[5]); gp[3] = pk2bf(e[6], e[7]);
    }
#pragma unroll
    for (int ct = 0; ct < 2; ++ct) {
      f32x4 c = {0.f, 0.f, 0.f, 0.f};
      c = __builtin_amdgcn_mfma_f32_16x16x32_bf16(bw1[ct], gb, c, 0, 0, 0);
      const int f0 = wbase + ct * 16 + quad * 4;
      uint2 pk;
      pk.x = pk2bf(sspf(c[0] + b1v[ct].x), sspf(c[1] + b1v[ct].y));
      pk.y = pk2bf(sspf(c[2] + b1v[ct].z), sspf(c[3] + b1v[ct].w));
      *(uint2*)(sH + j * HPAD + f0) = pk;
    }
  }
  __syncthreads();

  // ---- phase 2: W = h @ w2 (+b2 via C-init); consume global bf16 y ----
  float pagg[2] = {0.f, 0.f};
  for (int rt = 0; rt < ntiles; ++rt) {
    f32x4 acc[2];
    acc[0] = (f32x4){b2r[0], b2r[0], b2r[0], b2r[0]};
    acc[1] = (f32x4){b2r[1], b2r[1], b2r[1], b2r[1]};
#pragma unroll
    for (int kt = 0; kt < 4; ++kt) {
      const bf16x8 ah = *(const bf16x8*)(sH + (rt * 16 + lanelo) * HPAD + kt * 32 + quad * 8);
#pragma unroll
      for (int ct = 0; ct < 2; ++ct)
        acc[ct] = __builtin_amdgcn_mfma_f32_16x16x32_bf16(ah, bw2[ct * 4 + kt], acc[ct], 0, 0, 0);
    }
#pragma unroll
    for (int reg = 0; reg < 4; ++reg) {
      const int j = rt * 16 + quad * 4 + reg;
      const float sc = sScale[j];
      const unsigned short* yr =
          (const unsigned short*)(yIn + (size_t)(b0 + sNbr[j]) * NF) + wbase + lanelo;
#pragma unroll
      for (int ct = 0; ct < 2; ++ct)
        pagg[ct] = fmaf(sc * acc[ct][reg], bf2f(yr[ct * 16]), pagg[ct]);
    }
  }

  // ---- in-wave reduction over quads (j dim): 2 shuffles, no barrier ----
#pragma unroll
  for (int ct = 0; ct < 2; ++ct) {
    pagg[ct] += __shfl_xor(pagg[ct], 16, 64);
    pagg[ct] += __shfl_xor(pagg[ct], 32, 64);
  }
  if (quad == 0) {
    sAgg[wbase + lanelo] = pagg[0];
    sAgg[wbase + 16 + lanelo] = pagg[1];
  }
  __syncthreads();

  // ---- update GEMM 1: v2 = W12 @ agg (broadcast-B: every col identical) ----
  f32x4 c2[2] = {{0.f, 0.f, 0.f, 0.f}, {0.f, 0.f, 0.f, 0.f}};
#pragma unroll
  for (int kt = 0; kt < 4; ++kt) {
    const int k0 = kt * 32 + quad * 8;
    const bf16x8 b = pack8(*(const float4*)(sAgg + k0),
                           *(const float4*)(sAgg + k0 + 4));
#pragma unroll
    for (int ct = 0; ct < 2; ++ct) {
      const bf16x8 a = *(const bf16x8*)(W12Tl + (wbase + ct * 16 + lanelo) * 128 + k0);
      c2[ct] = __builtin_amdgcn_mfma_f32_16x16x32_bf16(a, b, c2[ct], 0, 0, 0);
    }
  }

  // ---- x += ssp(v2 + vang + b12); stage x_new for GEMM 2 ----
#pragma unroll
  for (int ct = 0; ct < 2; ++ct) {
    const int c0 = wbase + ct * 16 + quad * 4;
    const float4 dv = *(const float4*)(b12l + c0);
    const unsigned short* vp = (const unsigned short*)(vangL + (size_t)ga * 128 + c0);
    float* xp = x + (size_t)ga * 128 + c0;
    const float4 xv = *(const float4*)xp;
    float4 xo;
    xo.x = xv.x + sspf(c2[ct][0] + bf2f(vp[0]) + dv.x);
    xo.y = xv.y + sspf(c2[ct][1] + bf2f(vp[1]) + dv.y);
    xo.z = xv.z + sspf(c2[ct][2] + bf2f(vp[2]) + dv.z);
    xo.w = xv.w + sspf(c2[ct][3] + bf2f(vp[3]) + dv.w);
    if (lanelo == 0) {
      *(float4*)xp = xo;
      *(float4*)(sXn + c0) = xo;
    }
  }
  if (in2fTn == nullptr) return;
  __syncthreads();

  // ---- update GEMM 2: y_next = in2f[l+1]^T-frag @ x_new (broadcast-B) ----
  f32x4 c3[2] = {{0.f, 0.f, 0.f, 0.f}, {0.f, 0.f, 0.f, 0.f}};
#pragma unroll
  for (int kt = 0; kt < 4; ++kt) {
    const int k0 = kt * 32 + quad * 8;
    const bf16x8 b = pack8(*(const float4*)(sXn + k0),
                           *(const float4*)(sXn + k0 + 4));
#pragma unroll
    for (int ct = 0; ct < 2; ++ct) {
      const bf16x8 a = *(const bf16x8*)(in2fTn + (wbase + ct * 16 + lanelo) * 128 + k0);
      c3[ct] = __builtin_amdgcn_mfma_f32_16x16x32_bf16(a, b, c3[ct], 0, 0, 0);
    }
  }
  if (lanelo == 0) {
#pragma unroll
    for (int ct = 0; ct < 2; ++ct) {
      const int c0 = wbase + ct * 16 + quad * 4;
      uint2 pk; pk.x = pk2bf(c3[ct][0], c3[ct][1]); pk.y = pk2bf(c3[ct][2], c3[ct][3]);
      *(uint2*)(yOut + (size_t)ga * 128 + c0) = pk;
    }
  }
}

extern "C" void kernel_launch(void* const* d_in, const int* in_sizes, int n_in,
                              void* d_out, int out_size, void* d_ws, size_t ws_size,
                              hipStream_t stream) {
  (void)in_sizes; (void)n_in; (void)out_size; (void)ws_size;
  const int* zn = (const int*)d_in[0];
  const float* pos = (const float*)d_in[1];
  const int* nbr = (const int*)d_in[2];
  const int* nmask = (const int*)d_in[3];
  const float* Gi = (const float*)d_in[4];
  const float* emb = (const float*)d_in[5];
  const float* fw1 = (const float*)d_in[6];
  const float* fb1 = (const float*)d_in[7];
  const float* fw2 = (const float*)d_in[8];
  const float* fb2 = (const float*)d_in[9];
  const float* in2f = (const float*)d_in[10];
  const float* f2o = (const float*)d_in[11];
  const float* f2ob = (const float*)d_in[12];
  const float* dwp = (const float*)d_in[13];
  const float* dbp = (const float*)d_in[14];
  const float* awp = (const float*)d_in[15];

  float* x = (float*)d_out;                            // [B,A,D] fp32
  float* b12 = (float*)d_ws;                           // [3][128] fp32
  short* vangB = (short*)(b12 + 3 * 128);              // [3][B*A][128] bf16
  short* yA = vangB + (size_t)3 * NB * NA * ND;        // [B,A,F] bf16 (buf 0)
  short* yBb = yA + (size_t)NB * NA * NF;              // [B,A,F] bf16 (buf 1)
  short* w1T = yBb + (size_t)NB * NA * NF;             // [3][128][32]
  short* w2T = w1T + NW1;                              // [3][128][128]
  short* in2fT = w2T + NSQ;                            // [3][128][128]
  short* W12T = in2fT + NSQ;                           // [3][128][128]

  k_prep<<<PREP_BLK, 256, 0, stream>>>(
      fw1, fw2, in2f, awp, f2o, f2ob, dwp, dbp, emb, Gi, zn,
      w1T, w2T, in2fT, W12T, b12, vangB, x, yA);

  short* yin = yA;
  short* yout = yBb;
  for (int l = 0; l < 3; ++l) {
    k_fused<<<NB * NA, 256, 0, stream>>>(pos, nbr, nmask, yin,
        w1T + (size_t)l * 128 * 32, fb1 + (size_t)l * NF,
        w2T + (size_t)l * 16384, fb2 + (size_t)l * NF,
        x, vangB + (size_t)l * NB * NA * ND,
        W12T + (size_t)l * 16384, b12 + (size_t)l * 128,
        (l < 2) ? (in2fT + (size_t)(l + 1) * 16384) : nullptr, yout);
    short* tmp = yin; yin = yout; yout = tmp;
  }
}

// Round 2
// 214.730 us; speedup vs baseline: 1.2579x; 1.2579x over previous
//
#include <hip/hip_runtime.h>
#include <math.h>

#define NB 8
#define NA 512
#define NN 64
#define ND 128
#define NF 128
#define NG 25
#define NGA 512

typedef __attribute__((ext_vector_type(8))) short bf16x8;
typedef __attribute__((ext_vector_type(4))) float f32x4;

__device__ __forceinline__ float sspf(float v) {
  return fmaxf(v, 0.0f) + __logf(1.0f + __expf(-fabsf(v))) - 0.6931471805599453f;
}

__device__ __forceinline__ short f2bf(float x) {
  union { float f; unsigned u; } v; v.f = x;
  unsigned r = v.u + 0x7fffu + ((v.u >> 16) & 1u);   // RNE
  return (short)(r >> 16);
}

#if defined(__has_builtin)
#if __has_builtin(__builtin_amdgcn_cvt_pk_bf16_f32)
#define HAS_PKBF 1
#endif
#endif

__device__ __forceinline__ unsigned pk2bf(float a, float b) {
#ifdef HAS_PKBF
  typedef __attribute__((ext_vector_type(2))) __bf16 v2bf;
  union { v2bf v; unsigned u; } c;
  c.v = __builtin_amdgcn_cvt_pk_bf16_f32(a, b);
  return c.u;
#else
  union { float f; unsigned u; } x, y; x.f = a; y.f = b;
  const unsigned ra = (x.u + 0x7fffu + ((x.u >> 16) & 1u)) >> 16;
  const unsigned rb = (y.u + 0x7fffu + ((y.u >> 16) & 1u)) & 0xffff0000u;
  return ra | rb;
#endif
}

__device__ __forceinline__ float bf2f(unsigned short us) {
  union { unsigned u; float f; } v; v.u = ((unsigned)us) << 16; return v.f;
}

__device__ __forceinline__ bf16x8 pack8(float4 a, float4 b) {
  bf16x8 r;
  unsigned* p = (unsigned*)&r;
  p[0] = pk2bf(a.x, a.y); p[1] = pk2bf(a.z, a.w);
  p[2] = pk2bf(b.x, b.y); p[3] = pk2bf(b.z, b.w);
  return r;
}

// W^T-style fragment built from row-major M[k][n]: elem i = bf16(M[k0q+i][n])
__device__ __forceinline__ bf16x8 fragT(const float* __restrict__ M, int ldn,
                                        int n, int k0q) {
  float e[8];
#pragma unroll
  for (int i = 0; i < 8; ++i) e[i] = M[(size_t)(k0q + i) * ldn + n];
  bf16x8 r; unsigned* p = (unsigned*)&r;
  p[0] = pk2bf(e[0], e[1]); p[1] = pk2bf(e[2], e[3]);
  p[2] = pk2bf(e[4], e[5]); p[3] = pk2bf(e[6], e[7]);
  return r;
}

#define NW1 (3 * 128 * 32)      // 12288
#define NSQ (3 * 128 * 128)     // 49152
#define NAWT (3 * 128 * 512)    // 196608
#define NGIB (NB * NA * NGA)    // 2097152

// ---- k_prep1 grid layout (all blocks independent) ----
#define TT_BLK 96               // fw2,in2f transposes: 6 mats x 16 tiles
#define AT_BLK 192              // aw transpose: 3 mats x 64 tiles -> awT [128][512] bf16
#define W1_BLK 48               // w1T scalar transpose
#define PF_BLK 24               // W12 fuse + b12
#define GB_BLK 1024             // Gi -> bf16 pack
#define P1_AT (TT_BLK)          // 96
#define P1_W1 (P1_AT + AT_BLK)  // 288
#define P1_PF (P1_W1 + W1_BLK)  // 336
#define P1_GB (P1_PF + PF_BLK)  // 360
#define P1_TOT (P1_GB + GB_BLK) // 1384

// ---- k_prep2 grid layout ----
#define VA_BLK 768              // vang (vectorized bf16)
#define P2_TOT (VA_BLK + 256)   // + y0/x init = 1024

// ============== prep1: transposes + bf16 packs (independent) ==============
__global__ __launch_bounds__(256) void k_prep1(
    const float* __restrict__ fw1, const float* __restrict__ fw2,
    const float* __restrict__ in2f, const float* __restrict__ aw,
    const float* __restrict__ f2o, const float* __restrict__ f2ob,
    const float* __restrict__ dw, const float* __restrict__ db,
    const float* __restrict__ Gi,
    short* __restrict__ w1T, short* __restrict__ w2T,
    short* __restrict__ in2fT, short* __restrict__ W12T,
    float* __restrict__ b12, short* __restrict__ awT,
    short* __restrict__ GiB) {
  __shared__ short sTile[32][33];
  const int bx = blockIdx.x;
  const int t = threadIdx.x;
  const int lane = t & 63, wave = t >> 6;
  const int lanelo = lane & 15, quad = lane >> 4;
  const int wbase = wave << 5;

  if (bx < TT_BLK) {
    // ---- tiled transpose: fw2 -> w2T, in2f -> in2fT (bf16, [n][k]) ----
    const int mat = bx >> 4, tile = bx & 15;
    const int l = mat >> 1, which = mat & 1;
    const float* src = (which ? in2f : fw2) + (size_t)l * 16384;
    short* dst = (which ? in2fT : w2T) + (size_t)l * 16384;
    const int tk0 = (tile >> 2) << 5, tn0 = (tile & 3) << 5;
    const int tr = t >> 3, tc4 = (t & 7) << 2;
    const float4 v = *(const float4*)(src + (size_t)(tk0 + tr) * 128 + tn0 + tc4);
    sTile[tr][tc4] = f2bf(v.x); sTile[tr][tc4 + 1] = f2bf(v.y);
    sTile[tr][tc4 + 2] = f2bf(v.z); sTile[tr][tc4 + 3] = f2bf(v.w);
    __syncthreads();
    short o[4];
#pragma unroll
    for (int j = 0; j < 4; ++j) o[j] = sTile[tc4 + j][tr];
    uint2 pk;
    pk.x = ((unsigned)(unsigned short)o[0]) | (((unsigned)(unsigned short)o[1]) << 16);
    pk.y = ((unsigned)(unsigned short)o[2]) | (((unsigned)(unsigned short)o[3]) << 16);
    *(uint2*)(dst + (size_t)(tn0 + tr) * 128 + tk0 + tc4) = pk;
    return;
  }
  if (bx < P1_W1) {
    // ---- aw [512][128] -> awT [128][512] bf16 ----
    const int ab = bx - P1_AT;
    const int l = ab >> 6, tile = ab & 63;
    const int tk0 = (tile >> 2) << 5, tn0 = (tile & 3) << 5;   // k:16 tiles, n:4 tiles
    const float* src = aw + (size_t)l * 65536;
    short* dst = awT + (size_t)l * 65536;
    const int tr = t >> 3, tc4 = (t & 7) << 2;
    const float4 v = *(const float4*)(src + (size_t)(tk0 + tr) * 128 + tn0 + tc4);
    sTile[tr][tc4] = f2bf(v.x); sTile[tr][tc4 + 1] = f2bf(v.y);
    sTile[tr][tc4 + 2] = f2bf(v.z); sTile[tr][tc4 + 3] = f2bf(v.w);
    __syncthreads();
    short o[4];
#pragma unroll
    for (int j = 0; j < 4; ++j) o[j] = sTile[tc4 + j][tr];
    uint2 pk;
    pk.x = ((unsigned)(unsigned short)o[0]) | (((unsigned)(unsigned short)o[1]) << 16);
    pk.y = ((unsigned)(unsigned short)o[2]) | (((unsigned)(unsigned short)o[3]) << 16);
    *(uint2*)(dst + (size_t)(tn0 + tr) * 512 + tk0 + tc4) = pk;
    return;
  }
  if (bx < P1_PF) {
    // ---- w1T[l][n][k] (k padded 25->32) ----
    const int idx = (bx - P1_W1) * 256 + t;
    const int l = idx >> 12, r = idx & 4095, n = r >> 5, k = r & 31;
    w1T[idx] = (k < NG) ? f2bf(fw1[(size_t)l * NG * NF + k * NF + n]) : (short)0;
    return;
  }
  if (bx < P1_GB) {
    // ---- W12 = f2o@dw (bf16 [j][i]), b12 = f2ob@dw + db ----
    const int fb = bx - P1_PF;
    const int l = fb >> 3, xi = fb & 7;
    const int i = (xi << 4) + lanelo;
    const float* f2o_l = f2o + (size_t)l * 16384;
    const float* dw_l = dw + (size_t)l * 16384;
    short* W12T_l = W12T + (size_t)l * 16384;
    f32x4 c[2] = {{0.f, 0.f, 0.f, 0.f}, {0.f, 0.f, 0.f, 0.f}};
#pragma unroll
    for (int kt = 0; kt < 4; ++kt) {
      const int k0 = kt * 32 + quad * 8;
      const bf16x8 b = pack8(*(const float4*)(f2o_l + (size_t)i * 128 + k0),
                             *(const float4*)(f2o_l + (size_t)i * 128 + k0 + 4));
#pragma unroll
      for (int ct = 0; ct < 2; ++ct) {
        const bf16x8 a = fragT(dw_l, 128, wbase + ct * 16 + lanelo, k0);
        c[ct] = __builtin_amdgcn_mfma_f32_16x16x32_bf16(a, b, c[ct], 0, 0, 0);
      }
    }
#pragma unroll
    for (int ct = 0; ct < 2; ++ct)
#pragma unroll
      for (int reg = 0; reg < 4; ++reg) {
        const int j = wbase + ct * 16 + quad * 4 + reg;
        W12T_l[(size_t)j * 128 + i] = f2bf(c[ct][reg]);
      }
    if (xi == 0 && t < 128) {
      float acc = db[(size_t)l * 128 + t];
      for (int k = 0; k < 128; ++k)
        acc += f2ob[(size_t)l * 128 + k] * dw_l[(size_t)k * 128 + t];
      b12[(size_t)l * 128 + t] = acc;
    }
    return;
  }
  // ---- Gi fp32 -> GiB bf16 (vectorized pack) ----
  {
    const int idx = ((bx - P1_GB) << 8) + t;      // 0..262143, 8 elems each
    const float* g = Gi + (size_t)idx * 8;
    const bf16x8 v = pack8(*(const float4*)g, *(const float4*)(g + 4));
    *(bf16x8*)(GiB + (size_t)idx * 8) = v;
  }
}

// ============== prep2: vang + y0 (all-vectorized bf16 MFMA) ================
__global__ __launch_bounds__(256) void k_prep2(
    const float* __restrict__ emb, const int* __restrict__ zn,
    const short* __restrict__ GiB, const short* __restrict__ awT,
    const short* __restrict__ in2fT,
    short* __restrict__ vangB, float* __restrict__ x, short* __restrict__ yB) {
  const int bx = blockIdx.x;
  const int t = threadIdx.x;
  const int lane = t & 63, wave = t >> 6;
  const int lanelo = lane & 15, quad = lane >> 4;
  const int wbase = wave << 5;

  if (bx < VA_BLK) {
    // ---- vangB[l] = bf16(GiB @ awT[l]) ----
    const int l = bx >> 8;
    const int row = ((bx & 255) << 4) + lanelo;
    const short* awT_l = awT + (size_t)l * 65536;
    f32x4 c[2] = {{0.f, 0.f, 0.f, 0.f}, {0.f, 0.f, 0.f, 0.f}};
#pragma unroll
    for (int kt = 0; kt < 16; ++kt) {
      const int k0 = kt * 32 + quad * 8;
      const bf16x8 b = *(const bf16x8*)(GiB + (size_t)row * NGA + k0);
#pragma unroll
      for (int ct = 0; ct < 2; ++ct) {
        const bf16x8 a = *(const bf16x8*)(awT_l + (size_t)(wbase + ct * 16 + lanelo) * 512 + k0);
        c[ct] = __builtin_amdgcn_mfma_f32_16x16x32_bf16(a, b, c[ct], 0, 0, 0);
      }
    }
    short* vrow = vangB + ((size_t)l * NB * NA + row) * 128;
#pragma unroll
    for (int ct = 0; ct < 2; ++ct) {
      uint2 pk; pk.x = pk2bf(c[ct][0], c[ct][1]); pk.y = pk2bf(c[ct][2], c[ct][3]);
      *(uint2*)(vrow + wbase + ct * 16 + quad * 4) = pk;
    }
    return;
  }
  // ---- y0 = bf16(emb[zn] @ in2f[0]); wave 0 also writes x = emb[zn] ----
  {
    const int row = ((bx - VA_BLK) << 4) + lanelo;
    const float* erow = emb + (size_t)zn[row] * ND;
    f32x4 c[2] = {{0.f, 0.f, 0.f, 0.f}, {0.f, 0.f, 0.f, 0.f}};
#pragma unroll
    for (int kt = 0; kt < 4; ++kt) {
      const int k0 = kt * 32 + quad * 8;
      const float4 e0 = *(const float4*)(erow + k0);
      const float4 e1 = *(const float4*)(erow + k0 + 4);
      if (wave == 0) {
        *(float4*)(x + (size_t)row * ND + k0) = e0;
        *(float4*)(x + (size_t)row * ND + k0 + 4) = e1;
      }
      const bf16x8 b = pack8(e0, e1);
#pragma unroll
      for (int ct = 0; ct < 2; ++ct) {
        const bf16x8 a = *(const bf16x8*)(in2fT + (size_t)(wbase + ct * 16 + lanelo) * 128 + k0);
        c[ct] = __builtin_amdgcn_mfma_f32_16x16x32_bf16(a, b, c[ct], 0, 0, 0);
      }
    }
#pragma unroll
    for (int ct = 0; ct < 2; ++ct) {
      const int c0 = wbase + ct * 16 + quad * 4;
      uint2 pk; pk.x = pk2bf(c[ct][0], c[ct][1]); pk.y = pk2bf(c[ct][2], c[ct][3]);
      *(uint2*)(yB + (size_t)row * 128 + c0) = pk;
    }
  }
}

// ================= fused CFConv with neighbor compaction ===================
// One barrier total. Each wave redundantly computes distances+ballot into
// PRIVATE per-wave LDS metadata (no cross-wave race, no barrier needed).
// y-gather values prefetched into registers before phase 1 (latency hiding).
#define HPAD 136
__global__ __launch_bounds__(256) void k_cfconv(
    const float* __restrict__ pos, const int* __restrict__ nbr,
    const int* __restrict__ nmask, const short* __restrict__ yB,
    const short* __restrict__ w1T, const float* __restrict__ b1,
    const short* __restrict__ w2T, const float* __restrict__ b2,
    short* __restrict__ aggB) {
  __shared__ alignas(16) short sH[NN * HPAD];
  __shared__ float sRw[4][NN];
  __shared__ int sNw[4][NN];

  const int t = threadIdx.x;
  const int ga = blockIdx.x;
  const int b0 = ga & ~(NA - 1);
  const int lane = t & 63;
  const int wave = t >> 6;
  const int lanelo = lane & 15;
  const int quad = lane >> 4;
  const int wbase = wave << 5;     // this wave's 32 f-cols

  bf16x8 bw1[2];
  bf16x8 bw2[8];
#pragma unroll
  for (int ct = 0; ct < 2; ++ct) {
    const int n = wbase + ct * 16 + lanelo;
    bw1[ct] = *(const bf16x8*)(w1T + n * 32 + quad * 8);
#pragma unroll
    for (int kt = 0; kt < 4; ++kt)
      bw2[ct * 4 + kt] = *(const bf16x8*)(w2T + n * 128 + kt * 32 + quad * 8);
  }
  float b2r[2];
#pragma unroll
  for (int ct = 0; ct < 2; ++ct) b2r[ct] = b2[wbase + ct * 16 + lanelo];
  float4 b1v[2];
#pragma unroll
  for (int ct = 0; ct < 2; ++ct)
    b1v[ct] = *(const float4*)(b1 + wbase + ct * 16 + quad * 4);

  // ---- per-wave distances + ballot compaction (no barrier) ----
  const int nj = nbr[(size_t)ga * NN + lane];
  const int mk = nmask[(size_t)ga * NN + lane];
  const float px = pos[(size_t)ga * 3];
  const float py = pos[(size_t)ga * 3 + 1];
  const float pz = pos[(size_t)ga * 3 + 2];
  const float* pj = pos + (size_t)(b0 + nj) * 3;
  const float dx = pj[0] - px, dy = pj[1] - py, dz = pj[2] - pz;
  const float r = sqrtf(dx * dx + dy * dy + dz * dz + 1e-12f);
  const bool valid = (r <= 5.0f) && (mk != 0);
  sRw[wave][lane] = 1.0f; sNw[wave][lane] = 0;
  const unsigned long long m = __ballot(valid);
  const int posc = __popcll(m & ((1ull << lane) - 1ull));
  if (valid) { sRw[wave][posc] = r; sNw[wave][posc] = nj; }
  const int nv = (int)__popcll(m);
  const int ntiles = (nv + 15) >> 4;

  // ---- prefetch y-gather values (hide global latency under phase 1) ----
  unsigned yv[4][4];
#pragma unroll
  for (int rt = 0; rt < 4; ++rt) {
    if (rt < ntiles) {                      // wave-uniform branch
#pragma unroll
      for (int reg = 0; reg < 4; ++reg) {
        const int j = rt * 16 + quad * 4 + reg;
        const unsigned short* yr =
            (const unsigned short*)(yB + (size_t)(b0 + sNw[wave][j]) * NF) + wbase + lanelo;
        yv[rt][reg] = (unsigned)yr[0] | ((unsigned)yr[16] << 16);
      }
    }
  }

  const float step = 3.8f / 24.0f;
  const float coef = -0.5f / (step * step);

  // ---- phase 1: h = ssp(f @ w1 + b1) for compacted tiles ----
  for (int jt = 0; jt < ntiles; ++jt) {
    const int j = jt * 16 + lanelo;
    const float rj = sRw[wave][j];
    bf16x8 gb;
    {
      float e[8];
#pragma unroll
      for (int i = 0; i < 8; ++i) {
        const int g = quad * 8 + i;
        const float d = rj - (1.2f + step * (float)g);
        e[i] = (g < NG) ? __expf(coef * d * d) : 0.0f;
      }
      unsigned* gp = (unsigned*)&gb;
      gp[0] = pk2bf(e[0], e[1]); gp[1] = pk2bf(e[2], e[3]);
      gp[2] = pk2bf(e[4], e[5]); gp[3] = pk2bf(e[6], e[7]);
    }
#pragma unroll
    for (int ct = 0; ct < 2; ++ct) {
      f32x4 c = {0.f, 0.f, 0.f, 0.f};
      c = __builtin_amdgcn_mfma_f32_16x16x32_bf16(bw1[ct], gb, c, 0, 0, 0);
      const int f0 = wbase + ct * 16 + quad * 4;
      uint2 pk;
      pk.x = pk2bf(sspf(c[0] + b1v[ct].x), sspf(c[1] + b1v[ct].y));
      pk.y = pk2bf(sspf(c[2] + b1v[ct].z), sspf(c[3] + b1v[ct].w));
      *(uint2*)(sH + j * HPAD + f0) = pk;
    }
  }
  __syncthreads();

  // ---- phase 2: W = h @ w2 (+b2 via C-init); multiply prefetched y ----
  float pagg[2] = {0.f, 0.f};
  for (int rt = 0; rt < ntiles; ++rt) {
    f32x4 acc[2];
    acc[0] = (f32x4){b2r[0], b2r[0], b2r[0], b2r[0]};
    acc[1] = (f32x4){b2r[1], b2r[1], b2r[1], b2r[1]};
#pragma unroll
    for (int kt = 0; kt < 4; ++kt) {
      const bf16x8 ah = *(const bf16x8*)(sH + (rt * 16 + lanelo) * HPAD + kt * 32 + quad * 8);
#pragma unroll
      for (int ct = 0; ct < 2; ++ct)
        acc[ct] = __builtin_amdgcn_mfma_f32_16x16x32_bf16(ah, bw2[ct * 4 + kt], acc[ct], 0, 0, 0);
    }
#pragma unroll
    for (int reg = 0; reg < 4; ++reg) {
      const int j = rt * 16 + quad * 4 + reg;
      const float sc = (j < nv) ? 1.0f : 0.0f;
      union { unsigned u; float f; } y0, y1;
      y0.u = yv[rt][reg] << 16;
      y1.u = yv[rt][reg] & 0xffff0000u;
      pagg[0] = fmaf(sc * acc[0][reg], y0.f, pagg[0]);
      pagg[1] = fmaf(sc * acc[1][reg], y1.f, pagg[1]);
    }
  }

  // ---- in-wave reduction over quads (j dim): 2 shuffles, no barrier ----
#pragma unroll
  for (int ct = 0; ct < 2; ++ct) {
    pagg[ct] += __shfl_xor(pagg[ct], 16, 64);
    pagg[ct] += __shfl_xor(pagg[ct], 32, 64);
  }
  if (quad == 0) {
    aggB[(size_t)ga * NF + wbase + lanelo] = f2bf(pagg[0]);
    aggB[(size_t)ga * NF + wbase + 16 + lanelo] = f2bf(pagg[1]);
  }
}

// ================= per-layer update (fused W12, 2 GEMMs) ===================
#define TPAD 136
__global__ __launch_bounds__(256) void k_upd(
    float* __restrict__ x, const short* __restrict__ aggB,
    const short* __restrict__ vangB,
    const short* __restrict__ W12Tl, const float* __restrict__ b12l,
    const short* __restrict__ in2fT, short* __restrict__ yB) {
  __shared__ alignas(16) short sT[16 * TPAD];
  const int t = threadIdx.x;
  const int lane = t & 63, wave = t >> 6;
  const int lanelo = lane & 15, quad = lane >> 4;
  const int wbase = wave << 5;
  const int row = (blockIdx.x << 4) + lanelo;

  f32x4 c2[2] = {{0.f, 0.f, 0.f, 0.f}, {0.f, 0.f, 0.f, 0.f}};
#pragma unroll
  for (int kt = 0; kt < 4; ++kt) {
    const bf16x8 b = *(const bf16x8*)(aggB + (size_t)row * 128 + kt * 32 + quad * 8);
#pragma unroll
    for (int ct = 0; ct < 2; ++ct) {
      const bf16x8 a = *(const bf16x8*)(W12Tl + (wbase + ct * 16 + lanelo) * 128 + kt * 32 + quad * 8);
      c2[ct] = __builtin_amdgcn_mfma_f32_16x16x32_bf16(a, b, c2[ct], 0, 0, 0);
    }
  }

#pragma unroll
  for (int ct = 0; ct < 2; ++ct) {
    const int c0 = wbase + ct * 16 + quad * 4;
    const float4 dv = *(const float4*)(b12l + c0);
    const unsigned short* vp = (const unsigned short*)(vangB + (size_t)row * 128 + c0);
    float* xp = x + (size_t)row * 128 + c0;
    const float4 xv = *(const float4*)xp;
    float4 xo;
    xo.x = xv.x + sspf(c2[ct][0] + bf2f(vp[0]) + dv.x);
    xo.y = xv.y + sspf(c2[ct][1] + bf2f(vp[1]) + dv.y);
    xo.z = xv.z + sspf(c2[ct][2] + bf2f(vp[2]) + dv.z);
    xo.w = xv.w + sspf(c2[ct][3] + bf2f(vp[3]) + dv.w);
    *(float4*)xp = xo;
    if (in2fT != nullptr) {
      uint2 pk; pk.x = pk2bf(xo.x, xo.y); pk.y = pk2bf(xo.z, xo.w);
      *(uint2*)(sT + lanelo * TPAD + c0) = pk;
    }
  }
  if (in2fT == nullptr) return;
  __syncthreads();

  f32x4 c3[2] = {{0.f, 0.f, 0.f, 0.f}, {0.f, 0.f, 0.f, 0.f}};
#pragma unroll
  for (int kt = 0; kt < 4; ++kt) {
    const bf16x8 b = *(const bf16x8*)(sT + lanelo * TPAD + kt * 32 + quad * 8);
#pragma unroll
    for (int ct = 0; ct < 2; ++ct) {
      const bf16x8 a = *(const bf16x8*)(in2fT + (wbase + ct * 16 + lanelo) * 128 + kt * 32 + quad * 8);
      c3[ct] = __builtin_amdgcn_mfma_f32_16x16x32_bf16(a, b, c3[ct], 0, 0, 0);
    }
  }
#pragma unroll
  for (int ct = 0; ct < 2; ++ct) {
    const int c0 = wbase + ct * 16 + quad * 4;
    uint2 pk; pk.x = pk2bf(c3[ct][0], c3[ct][1]); pk.y = pk2bf(c3[ct][2], c3[ct][3]);
    *(uint2*)(yB + (size_t)row * 128 + c0) = pk;
  }
}

extern "C" void kernel_launch(void* const* d_in, const int* in_sizes, int n_in,
                              void* d_out, int out_size, void* d_ws, size_t ws_size,
                              hipStream_t stream) {
  (void)in_sizes; (void)n_in; (void)out_size; (void)ws_size;
  const int* zn = (const int*)d_in[0];
  const float* pos = (const float*)d_in[1];
  const int* nbr = (const int*)d_in[2];
  const int* nmask = (const int*)d_in[3];
  const float* Gi = (const float*)d_in[4];
  const float* emb = (const float*)d_in[5];
  const float* fw1 = (const float*)d_in[6];
  const float* fb1 = (const float*)d_in[7];
  const float* fw2 = (const float*)d_in[8];
  const float* fb2 = (const float*)d_in[9];
  const float* in2f = (const float*)d_in[10];
  const float* f2o = (const float*)d_in[11];
  const float* f2ob = (const float*)d_in[12];
  const float* dwp = (const float*)d_in[13];
  const float* dbp = (const float*)d_in[14];
  const float* awp = (const float*)d_in[15];

  float* x = (float*)d_out;                            // [B,A,D] fp32
  float* b12 = (float*)d_ws;                           // [3][128] fp32
  short* vangB = (short*)(b12 + 3 * 128);              // [3][B*A][128] bf16
  short* yB = vangB + (size_t)3 * NB * NA * ND;        // [B,A,F] bf16
  short* aggB = yB + (size_t)NB * NA * NF;             // [B,A,F] bf16
  short* w1T = aggB + (size_t)NB * NA * NF;            // [3][128][32]
  short* w2T = w1T + NW1;                              // [3][128][128]
  short* in2fT = w2T + NSQ;                            // [3][128][128]
  short* W12T = in2fT + NSQ;                           // [3][128][128]
  short* awT = W12T + NSQ;                             // [3][128][512]
  short* GiB = awT + NAWT;                             // [B*A][512]

  k_prep1<<<P1_TOT, 256, 0, stream>>>(
      fw1, fw2, in2f, awp, f2o, f2ob, dwp, dbp, Gi,
      w1T, w2T, in2fT, W12T, b12, awT, GiB);
  k_prep2<<<P2_TOT, 256, 0, stream>>>(
      emb, zn, GiB, awT, in2fT, vangB, x, yB);
  for (int l = 0; l < 3; ++l) {
    k_cfconv<<<NB * NA, 256, 0, stream>>>(pos, nbr, nmask, yB,
        w1T + (size_t)l * 128 * 32, fb1 + (size_t)l * NF,
        w2T + (size_t)l * 16384, fb2 + (size_t)l * NF, aggB);
    k_upd<<<NB * NA / 16, 256, 0, stream>>>(x, aggB,
        vangB + (size_t)l * NB * NA * ND,
        W12T + (size_t)l * 16384, b12 + (size_t)l * 128,
        (l < 2) ? (in2fT + (size_t)(l + 1) * 16384) : nullptr, yB);
  }
}

// Round 4
// 187.424 us; speedup vs baseline: 1.4411x; 1.1457x over previous
//
#include <hip/hip_runtime.h>
#include <math.h>

#define NB 8
#define NA 512
#define NN 64
#define ND 128
#define NF 128
#define NG 25
#define NGA 512
#define TABN 1024

typedef __attribute__((ext_vector_type(8))) short bf16x8;
typedef __attribute__((ext_vector_type(4))) float f32x4;

__device__ __forceinline__ float sspf(float v) {
  return fmaxf(v, 0.0f) + __logf(1.0f + __expf(-fabsf(v))) - 0.6931471805599453f;
}

__device__ __forceinline__ short f2bf(float x) {
  union { float f; unsigned u; } v; v.f = x;
  unsigned r = v.u + 0x7fffu + ((v.u >> 16) & 1u);   // RNE
  return (short)(r >> 16);
}

#if defined(__has_builtin)
#if __has_builtin(__builtin_amdgcn_cvt_pk_bf16_f32)
#define HAS_PKBF 1
#endif
#endif

__device__ __forceinline__ unsigned pk2bf(float a, float b) {
#ifdef HAS_PKBF
  typedef __attribute__((ext_vector_type(2))) __bf16 v2bf;
  union { v2bf v; unsigned u; } c;
  c.v = __builtin_amdgcn_cvt_pk_bf16_f32(a, b);
  return c.u;
#else
  union { float f; unsigned u; } x, y; x.f = a; y.f = b;
  const unsigned ra = (x.u + 0x7fffu + ((x.u >> 16) & 1u)) >> 16;
  const unsigned rb = (y.u + 0x7fffu + ((y.u >> 16) & 1u)) & 0xffff0000u;
  return ra | rb;
#endif
}

__device__ __forceinline__ float bf2f(unsigned short us) {
  union { unsigned u; float f; } v; v.u = ((unsigned)us) << 16; return v.f;
}

__device__ __forceinline__ bf16x8 pack8(float4 a, float4 b) {
  bf16x8 r;
  unsigned* p = (unsigned*)&r;
  p[0] = pk2bf(a.x, a.y); p[1] = pk2bf(a.z, a.w);
  p[2] = pk2bf(b.x, b.y); p[3] = pk2bf(b.z, b.w);
  return r;
}

// W^T-style fragment built from row-major M[k][n]: elem i = bf16(M[k0q+i][n])
__device__ __forceinline__ bf16x8 fragT(const float* __restrict__ M, int ldn,
                                        int n, int k0q) {
  float e[8];
#pragma unroll
  for (int i = 0; i < 8; ++i) e[i] = M[(size_t)(k0q + i) * ldn + n];
  bf16x8 r; unsigned* p = (unsigned*)&r;
  p[0] = pk2bf(e[0], e[1]); p[1] = pk2bf(e[2], e[3]);
  p[2] = pk2bf(e[4], e[5]); p[3] = pk2bf(e[6], e[7]);
  return r;
}

#define NSQ (3 * 128 * 128)     // 49152
#define NAWT (3 * 128 * 512)    // 196608

// ---- k_prep1 grid layout (all blocks independent) ----
#define P1_TT 48                 // in2f transposes: 3 mats x 16 tiles
#define P1_AT (P1_TT + 192)      // aw transpose: 3 x 64 tiles          -> 240
#define P1_PF (P1_AT + 24)       // W12 fuse + b12                      -> 264
#define P1_GB (P1_PF + 1024)     // Gi -> bf16 pack                     -> 1288
#define P1_TOT (P1_GB + 96)      // filter table: 3 layers x 32 chunks  -> 1384

// ---- k_prep2 grid layout ----
#define VA_BLK 768               // vang (vectorized bf16)
#define P2_TOT (VA_BLK + 256)    // + y0/x init = 1024

// ============== prep1: transposes, packs, W12, filter table ===============
__global__ __launch_bounds__(256) void k_prep1(
    const float* __restrict__ fw1, const float* __restrict__ fb1,
    const float* __restrict__ fw2, const float* __restrict__ fb2,
    const float* __restrict__ in2f, const float* __restrict__ aw,
    const float* __restrict__ f2o, const float* __restrict__ f2ob,
    const float* __restrict__ dw, const float* __restrict__ db,
    const float* __restrict__ Gi,
    short* __restrict__ in2fT, short* __restrict__ W12T,
    float* __restrict__ b12, short* __restrict__ awT,
    short* __restrict__ GiB, float* __restrict__ Ttab) {
  __shared__ alignas(16) short sTile[32][33];
  __shared__ alignas(16) float sG[32][26];
  __shared__ alignas(16) float sHh[32][132];
  const int bx = blockIdx.x;
  const int t = threadIdx.x;
  const int lane = t & 63, wave = t >> 6;
  const int lanelo = lane & 15, quad = lane >> 4;
  const int wbase = wave << 5;

  if (bx < P1_TT) {
    // ---- tiled transpose: in2f -> in2fT (bf16, [n][k]) ----
    const int l = bx >> 4, tile = bx & 15;
    const float* src = in2f + (size_t)l * 16384;
    short* dst = in2fT + (size_t)l * 16384;
    const int tk0 = (tile >> 2) << 5, tn0 = (tile & 3) << 5;
    const int tr = t >> 3, tc4 = (t & 7) << 2;
    const float4 v = *(const float4*)(src + (size_t)(tk0 + tr) * 128 + tn0 + tc4);
    sTile[tr][tc4] = f2bf(v.x); sTile[tr][tc4 + 1] = f2bf(v.y);
    sTile[tr][tc4 + 2] = f2bf(v.z); sTile[tr][tc4 + 3] = f2bf(v.w);
    __syncthreads();
    short o[4];
#pragma unroll
    for (int j = 0; j < 4; ++j) o[j] = sTile[tc4 + j][tr];
    uint2 pk;
    pk.x = ((unsigned)(unsigned short)o[0]) | (((unsigned)(unsigned short)o[1]) << 16);
    pk.y = ((unsigned)(unsigned short)o[2]) | (((unsigned)(unsigned short)o[3]) << 16);
    *(uint2*)(dst + (size_t)(tn0 + tr) * 128 + tk0 + tc4) = pk;
    return;
  }
  if (bx < P1_AT) {
    // ---- aw [512][128] -> awT [128][512] bf16 ----
    const int ab = bx - P1_TT;
    const int l = ab >> 6, tile = ab & 63;
    const int tk0 = (tile >> 2) << 5, tn0 = (tile & 3) << 5;
    const float* src = aw + (size_t)l * 65536;
    short* dst = awT + (size_t)l * 65536;
    const int tr = t >> 3, tc4 = (t & 7) << 2;
    const float4 v = *(const float4*)(src + (size_t)(tk0 + tr) * 128 + tn0 + tc4);
    sTile[tr][tc4] = f2bf(v.x); sTile[tr][tc4 + 1] = f2bf(v.y);
    sTile[tr][tc4 + 2] = f2bf(v.z); sTile[tr][tc4 + 3] = f2bf(v.w);
    __syncthreads();
    short o[4];
#pragma unroll
    for (int j = 0; j < 4; ++j) o[j] = sTile[tc4 + j][tr];
    uint2 pk;
    pk.x = ((unsigned)(unsigned short)o[0]) | (((unsigned)(unsigned short)o[1]) << 16);
    pk.y = ((unsigned)(unsigned short)o[2]) | (((unsigned)(unsigned short)o[3]) << 16);
    *(uint2*)(dst + (size_t)(tn0 + tr) * 512 + tk0 + tc4) = pk;
    return;
  }
  if (bx < P1_PF) {
    // ---- W12 = f2o@dw (bf16 [j][i]), b12 = f2ob@dw + db ----
    const int fb = bx - P1_AT;
    const int l = fb >> 3, xi = fb & 7;
    const int i = (xi << 4) + lanelo;
    const float* f2o_l = f2o + (size_t)l * 16384;
    const float* dw_l = dw + (size_t)l * 16384;
    short* W12T_l = W12T + (size_t)l * 16384;
    f32x4 c[2] = {{0.f, 0.f, 0.f, 0.f}, {0.f, 0.f, 0.f, 0.f}};
#pragma unroll
    for (int kt = 0; kt < 4; ++kt) {
      const int k0 = kt * 32 + quad * 8;
      const bf16x8 b = pack8(*(const float4*)(f2o_l + (size_t)i * 128 + k0),
                             *(const float4*)(f2o_l + (size_t)i * 128 + k0 + 4));
#pragma unroll
      for (int ct = 0; ct < 2; ++ct) {
        const bf16x8 a = fragT(dw_l, 128, wbase + ct * 16 + lanelo, k0);
        c[ct] = __builtin_amdgcn_mfma_f32_16x16x32_bf16(a, b, c[ct], 0, 0, 0);
      }
    }
#pragma unroll
    for (int ct = 0; ct < 2; ++ct)
#pragma unroll
      for (int reg = 0; reg < 4; ++reg) {
        const int j = wbase + ct * 16 + quad * 4 + reg;
        W12T_l[(size_t)j * 128 + i] = f2bf(c[ct][reg]);
      }
    if (xi == 0 && t < 128) {
      float acc = db[(size_t)l * 128 + t];
      for (int k = 0; k < 128; ++k)
        acc += f2ob[(size_t)l * 128 + k] * dw_l[(size_t)k * 128 + t];
      b12[(size_t)l * 128 + t] = acc;
    }
    return;
  }
  if (bx < P1_GB) {
    // ---- Gi fp32 -> GiB bf16 (vectorized pack) ----
    const int idx = ((bx - P1_PF) << 8) + t;      // 8 elems each
    const float* g = Gi + (size_t)idx * 8;
    const bf16x8 v = pack8(*(const float4*)g, *(const float4*)(g + 4));
    *(bf16x8*)(GiB + (size_t)idx * 8) = v;
    return;
  }
  // ---- filter table: T[l][row][f] = (ssp(f(r)@w1+b1)@w2 + b2)[f], fp32 ----
  {
    const int tb = bx - P1_GB;                // 0..95
    const int l = tb >> 5;
    const int chunk = tb & 31;                // 32 rows each
    const float stepg = 3.8f / 24.0f;
    const float coef = -0.5f / (stepg * stepg);
    for (int idx = t; idx < 32 * 25; idx += 256) {
      const int rr = idx / 25, k = idx - rr * 25;
      const float rv = (float)(chunk * 32 + rr) * (5.0f / 1023.0f);
      const float d = rv - (1.2f + stepg * (float)k);
      sG[rr][k] = __expf(coef * d * d);
    }
    __syncthreads();
    const int f = t & 127, r2 = t >> 7;
    const float* w1 = fw1 + (size_t)l * NG * NF;
    const float bias1 = fb1[(size_t)l * NF + f];
    for (int rr = r2; rr < 32; rr += 2) {
      float acc = bias1;
#pragma unroll 5
      for (int k = 0; k < 25; ++k) acc = fmaf(sG[rr][k], w1[(size_t)k * NF + f], acc);
      sHh[rr][f] = sspf(acc);
    }
    __syncthreads();
    const float* w2 = fw2 + (size_t)l * 16384;
    const float bias2 = fb2[(size_t)l * NF + f];
    for (int rr = r2; rr < 32; rr += 2) {
      float acc = bias2;
#pragma unroll 8
      for (int k = 0; k < 128; ++k) acc = fmaf(sHh[rr][k], w2[(size_t)k * NF + f], acc);
      Ttab[((size_t)l * TABN + chunk * 32 + rr) * NF + f] = acc;
    }
  }
}

// ============== prep2: vang + y0 (all-vectorized bf16 MFMA) ================
__global__ __launch_bounds__(256) void k_prep2(
    const float* __restrict__ emb, const int* __restrict__ zn,
    const short* __restrict__ GiB, const short* __restrict__ awT,
    const short* __restrict__ in2fT,
    short* __restrict__ vangB, float* __restrict__ x, short* __restrict__ yB) {
  const int bx = blockIdx.x;
  const int t = threadIdx.x;
  const int lane = t & 63, wave = t >> 6;
  const int lanelo = lane & 15, quad = lane >> 4;
  const int wbase = wave << 5;

  if (bx < VA_BLK) {
    // ---- vangB[l] = bf16(GiB @ awT[l]) ----
    const int l = bx >> 8;
    const int row = ((bx & 255) << 4) + lanelo;
    const short* awT_l = awT + (size_t)l * 65536;
    f32x4 c[2] = {{0.f, 0.f, 0.f, 0.f}, {0.f, 0.f, 0.f, 0.f}};
#pragma unroll
    for (int kt = 0; kt < 16; ++kt) {
      const int k0 = kt * 32 + quad * 8;
      const bf16x8 b = *(const bf16x8*)(GiB + (size_t)row * NGA + k0);
#pragma unroll
      for (int ct = 0; ct < 2; ++ct) {
        const bf16x8 a = *(const bf16x8*)(awT_l + (size_t)(wbase + ct * 16 + lanelo) * 512 + k0);
        c[ct] = __builtin_amdgcn_mfma_f32_16x16x32_bf16(a, b, c[ct], 0, 0, 0);
      }
    }
    short* vrow = vangB + ((size_t)l * NB * NA + row) * 128;
#pragma unroll
    for (int ct = 0; ct < 2; ++ct) {
      uint2 pk; pk.x = pk2bf(c[ct][0], c[ct][1]); pk.y = pk2bf(c[ct][2], c[ct][3]);
      *(uint2*)(vrow + wbase + ct * 16 + quad * 4) = pk;
    }
    return;
  }
  // ---- y0 = bf16(emb[zn] @ in2f[0]); wave 0 also writes x = emb[zn] ----
  {
    const int row = ((bx - VA_BLK) << 4) + lanelo;
    const float* erow = emb + (size_t)zn[row] * ND;
    f32x4 c[2] = {{0.f, 0.f, 0.f, 0.f}, {0.f, 0.f, 0.f, 0.f}};
#pragma unroll
    for (int kt = 0; kt < 4; ++kt) {
      const int k0 = kt * 32 + quad * 8;
      const float4 e0 = *(const float4*)(erow + k0);
      const float4 e1 = *(const float4*)(erow + k0 + 4);
      if (wave == 0) {
        *(float4*)(x + (size_t)row * ND + k0) = e0;
        *(float4*)(x + (size_t)row * ND + k0 + 4) = e1;
      }
      const bf16x8 b = pack8(e0, e1);
#pragma unroll
      for (int ct = 0; ct < 2; ++ct) {
        const bf16x8 a = *(const bf16x8*)(in2fT + (size_t)(wbase + ct * 16 + lanelo) * 128 + k0);
        c[ct] = __builtin_amdgcn_mfma_f32_16x16x32_bf16(a, b, c[ct], 0, 0, 0);
      }
    }
#pragma unroll
    for (int ct = 0; ct < 2; ++ct) {
      const int c0 = wbase + ct * 16 + quad * 4;
      uint2 pk; pk.x = pk2bf(c[ct][0], c[ct][1]); pk.y = pk2bf(c[ct][2], c[ct][3]);
      *(uint2*)(yB + (size_t)row * 128 + c0) = pk;
    }
  }
}

// ====== fused layer: table-interp CFConv + interaction update ==============
// 256 blocks x 512 threads; block owns 16 atoms. Conv: each of 8 waves handles
// 2 atoms via ballot compaction + W(r) table lerp (no MFMA, no barriers).
// Update: 16-row MFMA GEMMs on LDS agg; y double-buffered across layers.
#define TPAD 136
#define APAD 136
__global__ __launch_bounds__(512) void k_layer(
    const float* __restrict__ pos, const int* __restrict__ nbr,
    const int* __restrict__ nmask, const short* __restrict__ yIn,
    const float* __restrict__ Tt,
    float* __restrict__ x, const short* __restrict__ vangL,
    const short* __restrict__ W12Tl, const float* __restrict__ b12l,
    const short* __restrict__ in2fTn, short* __restrict__ yOut) {
  __shared__ alignas(16) float2 sA[8][2][NN];  // lerp weights (1-fr, fr); 0 = padded
  __shared__ alignas(16) int2 sM[8][2][NN];    // (table row offset, y row offset)
  __shared__ alignas(16) float sAgg[16][APAD];
  __shared__ alignas(16) short sT[16 * TPAD];

  const int t = threadIdx.x;
  const int lane = t & 63;
  const int wave = t >> 6;            // 0..7
  const int lanelo = lane & 15;
  const int quad = lane >> 4;
  const int ga0 = blockIdx.x << 4;
  const int b0 = ga0 & ~(NA - 1);

  int nvv[2];
#pragma unroll
  for (int aa = 0; aa < 2; ++aa) {
    const int al = (wave << 1) + aa;
    const int ga = ga0 + al;
    sA[wave][aa][lane] = make_float2(0.f, 0.f);
    sM[wave][aa][lane] = make_int2(0, b0 * NF);
    const int nj = nbr[(size_t)ga * NN + lane];
    const int mk = nmask[(size_t)ga * NN + lane];
    const float px = pos[(size_t)ga * 3];
    const float py = pos[(size_t)ga * 3 + 1];
    const float pz = pos[(size_t)ga * 3 + 2];
    const float* pj = pos + (size_t)(b0 + nj) * 3;
    const float dx = pj[0] - px, dy = pj[1] - py, dz = pj[2] - pz;
    const float r = sqrtf(dx * dx + dy * dy + dz * dz + 1e-12f);
    const bool valid = (r <= 5.0f) && (mk != 0);
    const unsigned long long m = __ballot(valid);
    const int posc = __popcll(m & ((1ull << lane) - 1ull));
    const float tt = r * ((float)(TABN - 1) / 5.0f);
    int k0 = (int)tt; if (k0 > TABN - 2) k0 = TABN - 2;
    const float fr = tt - (float)k0;
    if (valid) {
      sA[wave][aa][posc] = make_float2(1.0f - fr, fr);
      sM[wave][aa][posc] = make_int2(k0 * NF, (b0 + nj) * NF);
    }
    nvv[aa] = (int)__popcll(m);
  }

  const unsigned short* yu = (const unsigned short*)yIn;
#pragma unroll
  for (int aa = 0; aa < 2; ++aa) {
    float acc0 = 0.f, acc1 = 0.f;
    const int ntc = (nvv[aa] + 3) & ~3;
    for (int c = 0; c < ntc; c += 4) {
#pragma unroll
      for (int u = 0; u < 4; ++u) {
        const float2 w = sA[wave][aa][c + u];
        const int2 off = sM[wave][aa][c + u];
        const float t0a = Tt[off.x + lane];
        const float t0b = Tt[off.x + lane + 64];
        const float t1a = Tt[off.x + NF + lane];
        const float t1b = Tt[off.x + NF + lane + 64];
        const float wva = fmaf(w.x, t0a, w.y * t1a);
        const float wvb = fmaf(w.x, t0b, w.y * t1b);
        acc0 = fmaf(wva, bf2f(yu[off.y + lane]), acc0);
        acc1 = fmaf(wvb, bf2f(yu[off.y + lane + 64]), acc1);
      }
    }
    const int al = (wave << 1) + aa;
    sAgg[al][lane] = acc0;
    sAgg[al][lane + 64] = acc1;
  }
  __syncthreads();

  // ---- update GEMM 1: v2 = W12 @ agg (16 atoms, 16 f-cols per wave) ----
  f32x4 c2 = {0.f, 0.f, 0.f, 0.f};
#pragma unroll
  for (int kt = 0; kt < 4; ++kt) {
    const float* ar = &sAgg[lanelo][kt * 32 + quad * 8];
    const bf16x8 b = pack8(*(const float4*)ar, *(const float4*)(ar + 4));
    const bf16x8 a = *(const bf16x8*)(W12Tl + ((wave << 4) + lanelo) * 128 + kt * 32 + quad * 8);
    c2 = __builtin_amdgcn_mfma_f32_16x16x32_bf16(a, b, c2, 0, 0, 0);
  }

  const int c0 = (wave << 4) + quad * 4;
  const int row = ga0 + lanelo;
  {
    const float4 dv = *(const float4*)(b12l + c0);
    const unsigned short* vp = (const unsigned short*)(vangL + (size_t)row * 128 + c0);
    float* xp = x + (size_t)row * 128 + c0;
    const float4 xv = *(const float4*)xp;
    float4 xo;
    xo.x = xv.x + sspf(c2[0] + bf2f(vp[0]) + dv.x);
    xo.y = xv.y + sspf(c2[1] + bf2f(vp[1]) + dv.y);
    xo.z = xv.z + sspf(c2[2] + bf2f(vp[2]) + dv.z);
    xo.w = xv.w + sspf(c2[3] + bf2f(vp[3]) + dv.w);
    *(float4*)xp = xo;
    if (in2fTn != nullptr) {
      uint2 pk; pk.x = pk2bf(xo.x, xo.y); pk.y = pk2bf(xo.z, xo.w);
      *(uint2*)(sT + lanelo * TPAD + c0) = pk;
    }
  }
  if (in2fTn == nullptr) return;
  __syncthreads();

  // ---- update GEMM 2: y_next = in2f[l+1] @ x_new ----
  f32x4 c3 = {0.f, 0.f, 0.f, 0.f};
#pragma unroll
  for (int kt = 0; kt < 4; ++kt) {
    const bf16x8 b = *(const bf16x8*)(sT + lanelo * TPAD + kt * 32 + quad * 8);
    const bf16x8 a = *(const bf16x8*)(in2fTn + ((wave << 4) + lanelo) * 128 + kt * 32 + quad * 8);
    c3 = __builtin_amdgcn_mfma_f32_16x16x32_bf16(a, b, c3, 0, 0, 0);
  }
  uint2 pk; pk.x = pk2bf(c3[0], c3[1]); pk.y = pk2bf(c3[2], c3[3]);
  *(uint2*)(yOut + (size_t)row * 128 + c0) = pk;
}

extern "C" void kernel_launch(void* const* d_in, const int* in_sizes, int n_in,
                              void* d_out, int out_size, void* d_ws, size_t ws_size,
                              hipStream_t stream) {
  (void)in_sizes; (void)n_in; (void)out_size; (void)ws_size;
  const int* zn = (const int*)d_in[0];
  const float* pos = (const float*)d_in[1];
  const int* nbr = (const int*)d_in[2];
  const int* nmask = (const int*)d_in[3];
  const float* Gi = (const float*)d_in[4];
  const float* emb = (const float*)d_in[5];
  const float* fw1 = (const float*)d_in[6];
  const float* fb1 = (const float*)d_in[7];
  const float* fw2 = (const float*)d_in[8];
  const float* fb2 = (const float*)d_in[9];
  const float* in2f = (const float*)d_in[10];
  const float* f2o = (const float*)d_in[11];
  const float* f2ob = (const float*)d_in[12];
  const float* dwp = (const float*)d_in[13];
  const float* dbp = (const float*)d_in[14];
  const float* awp = (const float*)d_in[15];

  float* x = (float*)d_out;                            // [B,A,D] fp32
  float* b12 = (float*)d_ws;                           // [3][128] fp32
  float* Ttab = b12 + 3 * 128;                         // [3][1024][128] fp32
  short* vangB = (short*)(Ttab + (size_t)3 * TABN * NF);  // [3][B*A][128] bf16
  short* yA = vangB + (size_t)3 * NB * NA * ND;        // [B,A,F] bf16 (buf 0)
  short* yBb = yA + (size_t)NB * NA * NF;              // [B,A,F] bf16 (buf 1)
  short* in2fT = yBb + (size_t)NB * NA * NF;           // [3][128][128]
  short* W12T = in2fT + NSQ;                           // [3][128][128]
  short* awT = W12T + NSQ;                             // [3][128][512]
  short* GiB = awT + NAWT;                             // [B*A][512]

  k_prep1<<<P1_TOT, 256, 0, stream>>>(
      fw1, fb1, fw2, fb2, in2f, awp, f2o, f2ob, dwp, dbp, Gi,
      in2fT, W12T, b12, awT, GiB, Ttab);
  k_prep2<<<P2_TOT, 256, 0, stream>>>(
      emb, zn, GiB, awT, in2fT, vangB, x, yA);

  short* yin = yA;
  short* yout = yBb;
  for (int l = 0; l < 3; ++l) {
    k_layer<<<NB * NA / 16, 512, 0, stream>>>(pos, nbr, nmask, yin,
        Ttab + (size_t)l * TABN * NF,
        x, vangB + (size_t)l * NB * NA * ND,
        W12T + (size_t)l * 16384, b12 + (size_t)l * 128,
        (l < 2) ? (in2fT + (size_t)(l + 1) * 16384) : nullptr, yout);
    short* tmp = yin; yin = yout; yout = tmp;
  }
}

// Round 5
// 149.749 us; speedup vs baseline: 1.8037x; 1.2516x over previous
//
#include <hip/hip_runtime.h>
#include <math.h>

#define NB 8
#define NA 512
#define NN 64
#define ND 128
#define NF 128
#define NG 25
#define NGA 512
#define TABN 1024

typedef __attribute__((ext_vector_type(8))) short bf16x8;
typedef __attribute__((ext_vector_type(4))) float f32x4;

__device__ __forceinline__ float sspf(float v) {
  return fmaxf(v, 0.0f) + __logf(1.0f + __expf(-fabsf(v))) - 0.6931471805599453f;
}

__device__ __forceinline__ short f2bf(float x) {
  union { float f; unsigned u; } v; v.f = x;
  unsigned r = v.u + 0x7fffu + ((v.u >> 16) & 1u);   // RNE
  return (short)(r >> 16);
}

#if defined(__has_builtin)
#if __has_builtin(__builtin_amdgcn_cvt_pk_bf16_f32)
#define HAS_PKBF 1
#endif
#endif

__device__ __forceinline__ unsigned pk2bf(float a, float b) {
#ifdef HAS_PKBF
  typedef __attribute__((ext_vector_type(2))) __bf16 v2bf;
  union { v2bf v; unsigned u; } c;
  c.v = __builtin_amdgcn_cvt_pk_bf16_f32(a, b);
  return c.u;
#else
  union { float f; unsigned u; } x, y; x.f = a; y.f = b;
  const unsigned ra = (x.u + 0x7fffu + ((x.u >> 16) & 1u)) >> 16;
  const unsigned rb = (y.u + 0x7fffu + ((y.u >> 16) & 1u)) & 0xffff0000u;
  return ra | rb;
#endif
}

__device__ __forceinline__ float bf2f(unsigned short us) {
  union { unsigned u; float f; } v; v.u = ((unsigned)us) << 16; return v.f;
}

__device__ __forceinline__ bf16x8 pack8(float4 a, float4 b) {
  bf16x8 r;
  unsigned* p = (unsigned*)&r;
  p[0] = pk2bf(a.x, a.y); p[1] = pk2bf(a.z, a.w);
  p[2] = pk2bf(b.x, b.y); p[3] = pk2bf(b.z, b.w);
  return r;
}

// W^T-style fragment built from row-major M[k][n]: elem i = bf16(M[k0q+i][n])
__device__ __forceinline__ bf16x8 fragT(const float* __restrict__ M, int ldn,
                                        int n, int k0q) {
  float e[8];
#pragma unroll
  for (int i = 0; i < 8; ++i) e[i] = M[(size_t)(k0q + i) * ldn + n];
  bf16x8 r; unsigned* p = (unsigned*)&r;
  p[0] = pk2bf(e[0], e[1]); p[1] = pk2bf(e[2], e[3]);
  p[2] = pk2bf(e[4], e[5]); p[3] = pk2bf(e[6], e[7]);
  return r;
}

#define NW1 (3 * 128 * 32)      // 12288
#define NSQ (3 * 128 * 128)     // 49152
#define NAWT (3 * 128 * 512)    // 196608

// ---- k_prep1 grid layout (all blocks independent) ----
#define P1_TT 96                 // fw2,in2f transposes: 6 mats x 16 tiles
#define P1_AT (P1_TT + 192)      // aw transpose: 3 x 64 tiles          -> 288
#define P1_W1 (P1_AT + 48)       // w1T scalar transpose                -> 336
#define P1_PF (P1_W1 + 24)       // W12 fuse + b12                      -> 360
#define P1_TOT (P1_PF + 1024)    // Gi -> bf16 pack                     -> 1384

// ---- k_prep2 grid layout ----
#define P2_VA 768                // vang (vectorized bf16)
#define P2_Y0 (P2_VA + 256)      // y0 + x init                         -> 1024
#define P2_TOT (P2_Y0 + 192)     // filter table via MFMA: 3 x 64       -> 1216

// ============== prep1: transposes + bf16 packs (independent) ==============
__global__ __launch_bounds__(256) void k_prep1(
    const float* __restrict__ fw1, const float* __restrict__ fw2,
    const float* __restrict__ in2f, const float* __restrict__ aw,
    const float* __restrict__ f2o, const float* __restrict__ f2ob,
    const float* __restrict__ dw, const float* __restrict__ db,
    const float* __restrict__ Gi,
    short* __restrict__ w1T, short* __restrict__ w2T,
    short* __restrict__ in2fT, short* __restrict__ W12T,
    float* __restrict__ b12, short* __restrict__ awT,
    short* __restrict__ GiB) {
  __shared__ alignas(16) short sTile[32][33];
  const int bx = blockIdx.x;
  const int t = threadIdx.x;
  const int lane = t & 63, wave = t >> 6;
  const int lanelo = lane & 15, quad = lane >> 4;
  const int wbase = wave << 5;

  if (bx < P1_TT) {
    // ---- tiled transpose: fw2 -> w2T, in2f -> in2fT (bf16, [n][k]) ----
    const int mat = bx >> 4, tile = bx & 15;
    const int l = mat >> 1, which = mat & 1;
    const float* src = (which ? in2f : fw2) + (size_t)l * 16384;
    short* dst = (which ? in2fT : w2T) + (size_t)l * 16384;
    const int tk0 = (tile >> 2) << 5, tn0 = (tile & 3) << 5;
    const int tr = t >> 3, tc4 = (t & 7) << 2;
    const float4 v = *(const float4*)(src + (size_t)(tk0 + tr) * 128 + tn0 + tc4);
    sTile[tr][tc4] = f2bf(v.x); sTile[tr][tc4 + 1] = f2bf(v.y);
    sTile[tr][tc4 + 2] = f2bf(v.z); sTile[tr][tc4 + 3] = f2bf(v.w);
    __syncthreads();
    short o[4];
#pragma unroll
    for (int j = 0; j < 4; ++j) o[j] = sTile[tc4 + j][tr];
    uint2 pk;
    pk.x = ((unsigned)(unsigned short)o[0]) | (((unsigned)(unsigned short)o[1]) << 16);
    pk.y = ((unsigned)(unsigned short)o[2]) | (((unsigned)(unsigned short)o[3]) << 16);
    *(uint2*)(dst + (size_t)(tn0 + tr) * 128 + tk0 + tc4) = pk;
    return;
  }
  if (bx < P1_AT) {
    // ---- aw [512][128] -> awT [128][512] bf16 ----
    const int ab = bx - P1_TT;
    const int l = ab >> 6, tile = ab & 63;
    const int tk0 = (tile >> 2) << 5, tn0 = (tile & 3) << 5;
    const float* src = aw + (size_t)l * 65536;
    short* dst = awT + (size_t)l * 65536;
    const int tr = t >> 3, tc4 = (t & 7) << 2;
    const float4 v = *(const float4*)(src + (size_t)(tk0 + tr) * 128 + tn0 + tc4);
    sTile[tr][tc4] = f2bf(v.x); sTile[tr][tc4 + 1] = f2bf(v.y);
    sTile[tr][tc4 + 2] = f2bf(v.z); sTile[tr][tc4 + 3] = f2bf(v.w);
    __syncthreads();
    short o[4];
#pragma unroll
    for (int j = 0; j < 4; ++j) o[j] = sTile[tc4 + j][tr];
    uint2 pk;
    pk.x = ((unsigned)(unsigned short)o[0]) | (((unsigned)(unsigned short)o[1]) << 16);
    pk.y = ((unsigned)(unsigned short)o[2]) | (((unsigned)(unsigned short)o[3]) << 16);
    *(uint2*)(dst + (size_t)(tn0 + tr) * 512 + tk0 + tc4) = pk;
    return;
  }
  if (bx < P1_W1) {
    // ---- w1T[l][n][k] (k padded 25->32) ----
    const int idx = (bx - P1_AT) * 256 + t;
    const int l = idx >> 12, r = idx & 4095, n = r >> 5, k = r & 31;
    w1T[idx] = (k < NG) ? f2bf(fw1[(size_t)l * NG * NF + k * NF + n]) : (short)0;
    return;
  }
  if (bx < P1_PF) {
    // ---- W12 = f2o@dw (bf16 [j][i]), b12 = f2ob@dw + db ----
    const int fb = bx - P1_W1;
    const int l = fb >> 3, xi = fb & 7;
    const int i = (xi << 4) + lanelo;
    const float* f2o_l = f2o + (size_t)l * 16384;
    const float* dw_l = dw + (size_t)l * 16384;
    short* W12T_l = W12T + (size_t)l * 16384;
    f32x4 c[2] = {{0.f, 0.f, 0.f, 0.f}, {0.f, 0.f, 0.f, 0.f}};
#pragma unroll
    for (int kt = 0; kt < 4; ++kt) {
      const int k0 = kt * 32 + quad * 8;
      const bf16x8 b = pack8(*(const float4*)(f2o_l + (size_t)i * 128 + k0),
                             *(const float4*)(f2o_l + (size_t)i * 128 + k0 + 4));
#pragma unroll
      for (int ct = 0; ct < 2; ++ct) {
        const bf16x8 a = fragT(dw_l, 128, wbase + ct * 16 + lanelo, k0);
        c[ct] = __builtin_amdgcn_mfma_f32_16x16x32_bf16(a, b, c[ct], 0, 0, 0);
      }
    }
#pragma unroll
    for (int ct = 0; ct < 2; ++ct)
#pragma unroll
      for (int reg = 0; reg < 4; ++reg) {
        const int j = wbase + ct * 16 + quad * 4 + reg;
        W12T_l[(size_t)j * 128 + i] = f2bf(c[ct][reg]);
      }
    if (xi == 0 && t < 128) {
      float acc = db[(size_t)l * 128 + t];
      for (int k = 0; k < 128; ++k)
        acc += f2ob[(size_t)l * 128 + k] * dw_l[(size_t)k * 128 + t];
      b12[(size_t)l * 128 + t] = acc;
    }
    return;
  }
  // ---- Gi fp32 -> GiB bf16 (vectorized pack) ----
  {
    const int idx = ((bx - P1_PF) << 8) + t;      // 8 elems each
    const float* g = Gi + (size_t)idx * 8;
    const bf16x8 v = pack8(*(const float4*)g, *(const float4*)(g + 4));
    *(bf16x8*)(GiB + (size_t)idx * 8) = v;
  }
}

// ======= prep2: vang + y0 + filter table (all-vectorized bf16 MFMA) ========
#define SHPAD 136
__global__ __launch_bounds__(256) void k_prep2(
    const float* __restrict__ emb, const int* __restrict__ zn,
    const short* __restrict__ GiB, const short* __restrict__ awT,
    const short* __restrict__ in2fT,
    const short* __restrict__ w1T, const short* __restrict__ w2T,
    const float* __restrict__ fb1, const float* __restrict__ fb2,
    short* __restrict__ vangB, float* __restrict__ x, short* __restrict__ yB,
    float* __restrict__ Ttab) {
  __shared__ alignas(16) short sH[16 * SHPAD];
  const int bx = blockIdx.x;
  const int t = threadIdx.x;
  const int lane = t & 63, wave = t >> 6;
  const int lanelo = lane & 15, quad = lane >> 4;
  const int wbase = wave << 5;

  if (bx < P2_VA) {
    // ---- vangB[l] = bf16(GiB @ awT[l]) ----
    const int l = bx >> 8;
    const int row = ((bx & 255) << 4) + lanelo;
    const short* awT_l = awT + (size_t)l * 65536;
    f32x4 c[2] = {{0.f, 0.f, 0.f, 0.f}, {0.f, 0.f, 0.f, 0.f}};
#pragma unroll
    for (int kt = 0; kt < 16; ++kt) {
      const int k0 = kt * 32 + quad * 8;
      const bf16x8 b = *(const bf16x8*)(GiB + (size_t)row * NGA + k0);
#pragma unroll
      for (int ct = 0; ct < 2; ++ct) {
        const bf16x8 a = *(const bf16x8*)(awT_l + (size_t)(wbase + ct * 16 + lanelo) * 512 + k0);
        c[ct] = __builtin_amdgcn_mfma_f32_16x16x32_bf16(a, b, c[ct], 0, 0, 0);
      }
    }
    short* vrow = vangB + ((size_t)l * NB * NA + row) * 128;
#pragma unroll
    for (int ct = 0; ct < 2; ++ct) {
      uint2 pk; pk.x = pk2bf(c[ct][0], c[ct][1]); pk.y = pk2bf(c[ct][2], c[ct][3]);
      *(uint2*)(vrow + wbase + ct * 16 + quad * 4) = pk;
    }
    return;
  }
  if (bx < P2_Y0) {
    // ---- y0 = bf16(emb[zn] @ in2f[0]); wave 0 also writes x = emb[zn] ----
    const int row = ((bx - P2_VA) << 4) + lanelo;
    const float* erow = emb + (size_t)zn[row] * ND;
    f32x4 c[2] = {{0.f, 0.f, 0.f, 0.f}, {0.f, 0.f, 0.f, 0.f}};
#pragma unroll
    for (int kt = 0; kt < 4; ++kt) {
      const int k0 = kt * 32 + quad * 8;
      const float4 e0 = *(const float4*)(erow + k0);
      const float4 e1 = *(const float4*)(erow + k0 + 4);
      if (wave == 0) {
        *(float4*)(x + (size_t)row * ND + k0) = e0;
        *(float4*)(x + (size_t)row * ND + k0 + 4) = e1;
      }
      const bf16x8 b = pack8(e0, e1);
#pragma unroll
      for (int ct = 0; ct < 2; ++ct) {
        const bf16x8 a = *(const bf16x8*)(in2fT + (size_t)(wbase + ct * 16 + lanelo) * 128 + k0);
        c[ct] = __builtin_amdgcn_mfma_f32_16x16x32_bf16(a, b, c[ct], 0, 0, 0);
      }
    }
#pragma unroll
    for (int ct = 0; ct < 2; ++ct) {
      const int c0 = wbase + ct * 16 + quad * 4;
      uint2 pk; pk.x = pk2bf(c[ct][0], c[ct][1]); pk.y = pk2bf(c[ct][2], c[ct][3]);
      *(uint2*)(yB + (size_t)row * 128 + c0) = pk;
    }
    return;
  }
  // ---- filter table via MFMA (verified cfconv scheme, 16 rows/block) ----
  {
    const int tb = bx - P2_Y0;                 // 0..191
    const int l = tb >> 6;
    const int chunk = tb & 63;                 // 16-row chunk
    const short* w1Tl = w1T + (size_t)l * 128 * 32;
    const short* w2Tl = w2T + (size_t)l * 16384;
    const float* b1 = fb1 + (size_t)l * NF;
    const float* b2 = fb2 + (size_t)l * NF;

    bf16x8 bw1[2];
    bf16x8 bw2[8];
#pragma unroll
    for (int ct = 0; ct < 2; ++ct) {
      const int n = wbase + ct * 16 + lanelo;
      bw1[ct] = *(const bf16x8*)(w1Tl + n * 32 + quad * 8);
#pragma unroll
      for (int kt = 0; kt < 4; ++kt)
        bw2[ct * 4 + kt] = *(const bf16x8*)(w2Tl + n * 128 + kt * 32 + quad * 8);
    }
    float4 b1v[2];
    float b2r[2];
#pragma unroll
    for (int ct = 0; ct < 2; ++ct) {
      b1v[ct] = *(const float4*)(b1 + wbase + ct * 16 + quad * 4);
      b2r[ct] = b2[wbase + ct * 16 + lanelo];
    }

    const float stepg = 3.8f / 24.0f;
    const float coef = -0.5f / (stepg * stepg);
    const float rv = (float)(chunk * 16 + lanelo) * (5.0f / 1023.0f);
    bf16x8 gb;
    {
      float e[8];
#pragma unroll
      for (int i = 0; i < 8; ++i) {
        const int g = quad * 8 + i;
        const float d = rv - (1.2f + stepg * (float)g);
        e[i] = (g < NG) ? __expf(coef * d * d) : 0.0f;
      }
      unsigned* gp = (unsigned*)&gb;
      gp[0] = pk2bf(e[0], e[1]); gp[1] = pk2bf(e[2], e[3]);
      gp[2] = pk2bf(e[4], e[5]); gp[3] = pk2bf(e[6], e[7]);
    }
    // phase 1: h = ssp(gauss @ w1 + b1) -> sH[row][f]
#pragma unroll
    for (int ct = 0; ct < 2; ++ct) {
      f32x4 c = {0.f, 0.f, 0.f, 0.f};
      c = __builtin_amdgcn_mfma_f32_16x16x32_bf16(bw1[ct], gb, c, 0, 0, 0);
      const int f0 = wbase + ct * 16 + quad * 4;
      uint2 pk;
      pk.x = pk2bf(sspf(c[0] + b1v[ct].x), sspf(c[1] + b1v[ct].y));
      pk.y = pk2bf(sspf(c[2] + b1v[ct].z), sspf(c[3] + b1v[ct].w));
      *(uint2*)(sH + lanelo * SHPAD + f0) = pk;
    }
    __syncthreads();
    // phase 2: T = h @ w2 + b2 -> Ttab fp32
    f32x4 acc[2];
    acc[0] = (f32x4){b2r[0], b2r[0], b2r[0], b2r[0]};
    acc[1] = (f32x4){b2r[1], b2r[1], b2r[1], b2r[1]};
#pragma unroll
    for (int kt = 0; kt < 4; ++kt) {
      const bf16x8 ah = *(const bf16x8*)(sH + lanelo * SHPAD + kt * 32 + quad * 8);
#pragma unroll
      for (int ct = 0; ct < 2; ++ct)
        acc[ct] = __builtin_amdgcn_mfma_f32_16x16x32_bf16(ah, bw2[ct * 4 + kt], acc[ct], 0, 0, 0);
    }
#pragma unroll
    for (int ct = 0; ct < 2; ++ct)
#pragma unroll
      for (int reg = 0; reg < 4; ++reg) {
        const int rrow = chunk * 16 + quad * 4 + reg;
        const int f = wbase + ct * 16 + lanelo;
        Ttab[((size_t)l * TABN + rrow) * NF + f] = acc[ct][reg];
      }
  }
}

// ====== fused layer: table-interp CFConv + interaction update ==============
// 256 blocks x 512 threads; block owns 16 atoms. Conv: each of 8 waves handles
// 2 atoms via ballot compaction + W(r) table lerp (no MFMA, no barriers).
// Update: 16-row MFMA GEMMs on LDS agg; y double-buffered across layers.
#define TPAD 136
#define APAD 136
__global__ __launch_bounds__(512) void k_layer(
    const float* __restrict__ pos, const int* __restrict__ nbr,
    const int* __restrict__ nmask, const short* __restrict__ yIn,
    const float* __restrict__ Tt,
    float* __restrict__ x, const short* __restrict__ vangL,
    const short* __restrict__ W12Tl, const float* __restrict__ b12l,
    const short* __restrict__ in2fTn, short* __restrict__ yOut) {
  __shared__ alignas(16) float2 sA[8][2][NN];  // lerp weights (1-fr, fr); 0 = padded
  __shared__ alignas(16) int2 sM[8][2][NN];    // (table row offset, y row offset)
  __shared__ alignas(16) float sAgg[16][APAD];
  __shared__ alignas(16) short sT[16 * TPAD];

  const int t = threadIdx.x;
  const int lane = t & 63;
  const int wave = t >> 6;            // 0..7
  const int lanelo = lane & 15;
  const int quad = lane >> 4;
  const int ga0 = blockIdx.x << 4;
  const int b0 = ga0 & ~(NA - 1);

  int nvv[2];
#pragma unroll
  for (int aa = 0; aa < 2; ++aa) {
    const int al = (wave << 1) + aa;
    const int ga = ga0 + al;
    sA[wave][aa][lane] = make_float2(0.f, 0.f);
    sM[wave][aa][lane] = make_int2(0, b0 * NF);
    const int nj = nbr[(size_t)ga * NN + lane];
    const int mk = nmask[(size_t)ga * NN + lane];
    const float px = pos[(size_t)ga * 3];
    const float py = pos[(size_t)ga * 3 + 1];
    const float pz = pos[(size_t)ga * 3 + 2];
    const float* pj = pos + (size_t)(b0 + nj) * 3;
    const float dx = pj[0] - px, dy = pj[1] - py, dz = pj[2] - pz;
    const float r = sqrtf(dx * dx + dy * dy + dz * dz + 1e-12f);
    const bool valid = (r <= 5.0f) && (mk != 0);
    const unsigned long long m = __ballot(valid);
    const int posc = __popcll(m & ((1ull << lane) - 1ull));
    const float tt = r * ((float)(TABN - 1) / 5.0f);
    int k0 = (int)tt; if (k0 > TABN - 2) k0 = TABN - 2;
    const float fr = tt - (float)k0;
    if (valid) {
      sA[wave][aa][posc] = make_float2(1.0f - fr, fr);
      sM[wave][aa][posc] = make_int2(k0 * NF, (b0 + nj) * NF);
    }
    nvv[aa] = (int)__popcll(m);
  }

  const unsigned short* yu = (const unsigned short*)yIn;
#pragma unroll
  for (int aa = 0; aa < 2; ++aa) {
    float acc0 = 0.f, acc1 = 0.f;
    const int ntc = (nvv[aa] + 3) & ~3;
    for (int c = 0; c < ntc; c += 4) {
#pragma unroll
      for (int u = 0; u < 4; ++u) {
        const float2 w = sA[wave][aa][c + u];
        const int2 off = sM[wave][aa][c + u];
        const float t0a = Tt[off.x + lane];
        const float t0b = Tt[off.x + lane + 64];
        const float t1a = Tt[off.x + NF + lane];
        const float t1b = Tt[off.x + NF + lane + 64];
        const float wva = fmaf(w.x, t0a, w.y * t1a);
        const float wvb = fmaf(w.x, t0b, w.y * t1b);
        acc0 = fmaf(wva, bf2f(yu[off.y + lane]), acc0);
        acc1 = fmaf(wvb, bf2f(yu[off.y + lane + 64]), acc1);
      }
    }
    const int al = (wave << 1) + aa;
    sAgg[al][lane] = acc0;
    sAgg[al][lane + 64] = acc1;
  }
  __syncthreads();

  // ---- update GEMM 1: v2 = W12 @ agg (16 atoms, 16 f-cols per wave) ----
  f32x4 c2 = {0.f, 0.f, 0.f, 0.f};
#pragma unroll
  for (int kt = 0; kt < 4; ++kt) {
    const float* ar = &sAgg[lanelo][kt * 32 + quad * 8];
    const bf16x8 b = pack8(*(const float4*)ar, *(const float4*)(ar + 4));
    const bf16x8 a = *(const bf16x8*)(W12Tl + ((wave << 4) + lanelo) * 128 + kt * 32 + quad * 8);
    c2 = __builtin_amdgcn_mfma_f32_16x16x32_bf16(a, b, c2, 0, 0, 0);
  }

  const int c0 = (wave << 4) + quad * 4;
  const int row = ga0 + lanelo;
  {
    const float4 dv = *(const float4*)(b12l + c0);
    const unsigned short* vp = (const unsigned short*)(vangL + (size_t)row * 128 + c0);
    float* xp = x + (size_t)row * 128 + c0;
    const float4 xv = *(const float4*)xp;
    float4 xo;
    xo.x = xv.x + sspf(c2[0] + bf2f(vp[0]) + dv.x);
    xo.y = xv.y + sspf(c2[1] + bf2f(vp[1]) + dv.y);
    xo.z = xv.z + sspf(c2[2] + bf2f(vp[2]) + dv.z);
    xo.w = xv.w + sspf(c2[3] + bf2f(vp[3]) + dv.w);
    *(float4*)xp = xo;
    if (in2fTn != nullptr) {
      uint2 pk; pk.x = pk2bf(xo.x, xo.y); pk.y = pk2bf(xo.z, xo.w);
      *(uint2*)(sT + lanelo * TPAD + c0) = pk;
    }
  }
  if (in2fTn == nullptr) return;
  __syncthreads();

  // ---- update GEMM 2: y_next = in2f[l+1] @ x_new ----
  f32x4 c3 = {0.f, 0.f, 0.f, 0.f};
#pragma unroll
  for (int kt = 0; kt < 4; ++kt) {
    const bf16x8 b = *(const bf16x8*)(sT + lanelo * TPAD + kt * 32 + quad * 8);
    const bf16x8 a = *(const bf16x8*)(in2fTn + ((wave << 4) + lanelo) * 128 + kt * 32 + quad * 8);
    c3 = __builtin_amdgcn_mfma_f32_16x16x32_bf16(a, b, c3, 0, 0, 0);
  }
  uint2 pk; pk.x = pk2bf(c3[0], c3[1]); pk.y = pk2bf(c3[2], c3[3]);
  *(uint2*)(yOut + (size_t)row * 128 + c0) = pk;
}

extern "C" void kernel_launch(void* const* d_in, const int* in_sizes, int n_in,
                              void* d_out, int out_size, void* d_ws, size_t ws_size,
                              hipStream_t stream) {
  (void)in_sizes; (void)n_in; (void)out_size; (void)ws_size;
  const int* zn = (const int*)d_in[0];
  const float* pos = (const float*)d_in[1];
  const int* nbr = (const int*)d_in[2];
  const int* nmask = (const int*)d_in[3];
  const float* Gi = (const float*)d_in[4];
  const float* emb = (const float*)d_in[5];
  const float* fw1 = (const float*)d_in[6];
  const float* fb1 = (const float*)d_in[7];
  const float* fw2 = (const float*)d_in[8];
  const float* fb2 = (const float*)d_in[9];
  const float* in2f = (const float*)d_in[10];
  const float* f2o = (const float*)d_in[11];
  const float* f2ob = (const float*)d_in[12];
  const float* dwp = (const float*)d_in[13];
  const float* dbp = (const float*)d_in[14];
  const float* awp = (const float*)d_in[15];

  float* x = (float*)d_out;                            // [B,A,D] fp32
  float* b12 = (float*)d_ws;                           // [3][128] fp32
  float* Ttab = b12 + 3 * 128;                         // [3][1024][128] fp32
  short* vangB = (short*)(Ttab + (size_t)3 * TABN * NF);  // [3][B*A][128] bf16
  short* yA = vangB + (size_t)3 * NB * NA * ND;        // [B,A,F] bf16 (buf 0)
  short* yBb = yA + (size_t)NB * NA * NF;              // [B,A,F] bf16 (buf 1)
  short* in2fT = yBb + (size_t)NB * NA * NF;           // [3][128][128]
  short* W12T = in2fT + NSQ;                           // [3][128][128]
  short* awT = W12T + NSQ;                             // [3][128][512]
  short* GiB = awT + NAWT;                             // [B*A][512]
  short* w1T = GiB + (size_t)NB * NA * NGA;            // [3][128][32]
  short* w2T = w1T + NW1;                              // [3][128][128]

  k_prep1<<<P1_TOT, 256, 0, stream>>>(
      fw1, fw2, in2f, awp, f2o, f2ob, dwp, dbp, Gi,
      w1T, w2T, in2fT, W12T, b12, awT, GiB);
  k_prep2<<<P2_TOT, 256, 0, stream>>>(
      emb, zn, GiB, awT, in2fT, w1T, w2T, fb1, fb2,
      vangB, x, yA, Ttab);

  short* yin = yA;
  short* yout = yBb;
  for (int l = 0; l < 3; ++l) {
    k_layer<<<NB * NA / 16, 512, 0, stream>>>(pos, nbr, nmask, yin,
        Ttab + (size_t)l * TABN * NF,
        x, vangB + (size_t)l * NB * NA * ND,
        W12T + (size_t)l * 16384, b12 + (size_t)l * 128,
        (l < 2) ? (in2fT + (size_t)(l + 1) * 16384) : nullptr, yout);
    short* tmp = yin; yin = yout; yout = tmp;
  }
}